// Round 2
// baseline (351.817 us; speedup 1.0000x reference)
//
#include <hip/hip_runtime.h>

#define HEADS 16
#define NQ    2048
#define NKV   4096
#define DH    128
#define PDIM  64

typedef __bf16 bf16_t;
typedef bf16_t bf16x8 __attribute__((ext_vector_type(8)));
typedef bf16_t bf16x4 __attribute__((ext_vector_type(4)));
typedef bf16_t bf16x2 __attribute__((ext_vector_type(2)));
typedef float  f32x4  __attribute__((ext_vector_type(4)));
typedef float  f32x16 __attribute__((ext_vector_type(16)));
typedef int    i32x4  __attribute__((ext_vector_type(4)));

typedef __attribute__((address_space(3))) unsigned int       lds_u32;
typedef __attribute__((address_space(1))) const unsigned int glb_u32;

__device__ __forceinline__ void dma16(const void* g, void* l) {
  __builtin_amdgcn_global_load_lds((glb_u32*)g, (lds_u32*)l, 16, 0, 0);
}

// ---------------------------------------------------------------------------
// prep: one 64x128 fp32 tile per block, staged through LDS so ALL global
// reads are 512B-contiguous per 32 lanes.
//   blocks [0,512):      Q tiles -> Qp (scaled by (1/8)*log2e)
//   blocks [512,1536):   K tiles -> Kp
//   blocks [1536,2560):  V tiles -> Vt (bf16 transpose)
// LDS tile is stored with a granule-level XOR swizzle (key = (row>>3)&7 on
// the f32x4 granule index). The V-transpose read (fixed d, 8 consecutive j)
// previously hit 8 banks with all 64 lanes (132*8 = 0 mod 32 -> 8-way
// imbalance, ~2.9x per m136); with the swizzle the read is a perfect 2-way
// (free) and the b128 writes stay balanced.
// LDS: 64*128 fp32 (32 KB) + 4*16*72 bf16 (9.2 KB) = 41 KB -> 3 blocks/CU.
// ---------------------------------------------------------------------------
__global__ __launch_bounds__(256) void prep_kernel(
    const float* __restrict__ Q, const float* __restrict__ K,
    const float* __restrict__ V, const float* __restrict__ R,
    bf16_t* __restrict__ Qp, bf16_t* __restrict__ Kp, bf16_t* __restrict__ Vt)
{
  __shared__ float  sF[64 * 128];       // swizzled granules, no pad needed
  __shared__ bf16_t sY[4][16 * 72];
  const int tid = threadIdx.x;
  const int bid = blockIdx.x;

  const int isQ = (bid < 512);
  const int isK = (bid >= 512) && (bid < 1536);

  // ---- coalesced 64x128 fp32 tile load -> LDS (swizzled) ----
  const float* src;
  long row0;
  if (isQ)      { src = Q; row0 = (long)bid * 64; }
  else if (isK) { src = K; row0 = (long)(bid - 512) * 64; }
  else          { src = V; row0 = (long)(bid - 1536) * 64; }
  const float* tp = src + row0 * DH;
#pragma unroll
  for (int rep = 0; rep < 8; ++rep) {
    const int slot = tid + rep * 256;          // 2048 granules: 64 rows x 32
    const int j = slot >> 5, g = slot & 31;
    f32x4 v = *(const f32x4*)(tp + j * DH + g * 4);
    *(f32x4*)(&sF[j * 128 + ((g ^ ((j >> 3) & 7)) << 2)]) = v;
  }
  __syncthreads();

  if (!isQ && !isK) {
    // ---- V transpose path ----
    const int vb = bid - 1536;
    const int h = vb >> 6, jt = vb & 63;
    bf16_t* op = Vt + (long)h * DH * NKV + jt * 64;
#pragma unroll
    for (int rep = 0; rep < 4; ++rep) {
      const int slot = tid + rep * 256;        // 1024 slots: 128 d x 8 j-groups
      const int d = slot >> 3, j8 = (slot & 7) * 8;
      const int key = slot & 7;                // == (j>>3)&7 for j in [j8,j8+8)
      const int gsw = (((d >> 2) ^ key) << 2) + (d & 3);
      bf16x8 w;
#pragma unroll
      for (int jj = 0; jj < 8; ++jj) w[jj] = (bf16_t)sF[(j8 + jj) * 128 + gsw];
      *(bf16x8*)(op + (long)d * NKV + j8) = w;
    }
    return;
  }

  // ---- projection path (Q or K) ----
  const int wave = tid >> 6, lane = tid & 63;
  const int n16  = lane & 15, quad = lane >> 4;
  const float scale = isQ ? 0.18033688011112042f : 1.0f;   // (1/8)*log2(e)
  bf16_t* Y = isQ ? Qp : Kp;

  // B fragments from R: B[k][n], n = nt*16+n16, k = kk*32 + quad*8 + j
  bf16x8 bfr[4][4];
#pragma unroll
  for (int nt = 0; nt < 4; ++nt) {
    const int n = nt * 16 + n16;
#pragma unroll
    for (int kk = 0; kk < 4; ++kk) {
      const int k0 = kk * 32 + quad * 8;
      bf16x8 b;
#pragma unroll
      for (int j = 0; j < 8; ++j) b[j] = (bf16_t)R[(k0 + j) * PDIM + n];
      bfr[nt][kk] = b;
    }
  }

  // A fragments from the LDS tile: row = wave*16 + n16, k = kk*32 + quad*8 + j
  const int arow = wave * 16 + n16;
  const int akey = (arow >> 3) & 7;
  bf16x8 a[4];
#pragma unroll
  for (int kk = 0; kk < 4; ++kk) {
    const int k0 = kk * 32 + quad * 8;
    const int g0 = k0 >> 2;
    f32x4 x0 = *(const f32x4*)(&sF[arow * 128 + ((g0 ^ akey) << 2)]);
    f32x4 x1 = *(const f32x4*)(&sF[arow * 128 + (((g0 + 1) ^ akey) << 2)]);
    bf16x8 av;
#pragma unroll
    for (int j = 0; j < 4; ++j) { av[j] = (bf16_t)(x0[j] * scale); av[4 + j] = (bf16_t)(x1[j] * scale); }
    a[kk] = av;
  }

  bf16_t* sy = sY[wave];
#pragma unroll
  for (int nt = 0; nt < 4; ++nt) {
    f32x4 acc = {0.f, 0.f, 0.f, 0.f};
#pragma unroll
    for (int kk = 0; kk < 4; ++kk)
      acc = __builtin_amdgcn_mfma_f32_16x16x32_bf16(a[kk], bfr[nt][kk], acc, 0, 0, 0);
#pragma unroll
    for (int r = 0; r < 4; ++r)
      sy[(quad * 4 + r) * 72 + nt * 16 + n16] = (bf16_t)acc[r];
  }
  // coalesced store: lane -> (row = lane>>2, colgroup = lane&3)
  const long xrow = row0 + wave * 16;
  const int row = lane >> 2, cg = lane & 3;
  bf16x8 w0 = *(const bf16x8*)(&sy[row * 72 + cg * 16]);
  bf16x8 w1 = *(const bf16x8*)(&sy[row * 72 + cg * 16 + 8]);
  *(bf16x8*)(Y + (xrow + row) * PDIM + cg * 16)     = w0;
  *(bf16x8*)(Y + (xrow + row) * PDIM + cg * 16 + 8) = w1;
}

// ---------------------------------------------------------------------------
// flash v7: exact v4 2-phase schedule (stage -> __syncthreads -> compute;
// NO DMA outstanding across ds_reads — round-1/r5 showed the compiler
// inserts conservative vmcnt(0) before ds_reads and spills when DMA is
// in flight across compute, 2x regression). Changes vs v4:
//   * KVB 64 -> 128: 4-wave/256-thread blocks (2 q-tiles merged), 512
//     blocks = exactly 2/CU. Barrier-drain events halve (16 -> 8),
//     per-wave DMA issue per iter unchanged (12 dma16), per-CU staging
//     bandwidth per iter unchanged (2 x 48 KB = 4 x 24 KB).
//   * LDS 48 KB: sK 128x64 (16 KB) + sV 128x128 (32 KB), single-buffered.
// Per-wave math identical to v4 (same register footprint, s loop 0..3).
// ---------------------------------------------------------------------------
__global__ __launch_bounds__(256, 2) void flash_kernel(
    const bf16_t* __restrict__ Qp, const bf16_t* __restrict__ Kp,
    const bf16_t* __restrict__ Vt, bf16_t* __restrict__ Opart,
    float* __restrict__ Lpart, float* __restrict__ Out,
    int splits, int iters)
{
  __shared__ char smem[49152];
  bf16_t* sK = (bf16_t*)smem;             // 128 rows x 64, swizzled chunks
  bf16_t* sV = (bf16_t*)(smem + 16384);   // 128 rows x 128, swizzled

  const int tid  = threadIdx.x;
  const int wave = tid >> 6, lane = tid & 63;
  const int l31  = lane & 31, h = lane >> 5;

  const int head = blockIdx.x & 15;      // XCD round-robin -> 2 heads/XCD
  const int qt   = (blockIdx.x >> 4) & 7;
  const int sp   = blockIdx.x >> 7;

  const int qbase = qt * 256 + wave * 64;
  const int kv0   = sp * (128 * iters);

  // persistent Q B-frags: B[k=p][n=q], q = qsub*32+l31, p = k*16 + 8h + j
  bf16x8 qf[2][4];
#pragma unroll
  for (int qsub = 0; qsub < 2; ++qsub)
#pragma unroll
    for (int k = 0; k < 4; ++k)
      qf[qsub][k] = *(const bf16x8*)(Qp + ((long)head * NQ + qbase + qsub * 32 + l31) * PDIM
                                     + k * 16 + h * 8);

  f32x16 o[2][4] = {};          // O^T accum: [qsub][dsub], C layout
  float rsum[2] = {0.f, 0.f};   // per-lane partial row sums

  const bf16_t* kpH = Kp + (long)head * NKV * PDIM;
  const bf16_t* vtH = Vt + (long)head * DH * NKV;

  const int r8  = lane >> 3;
  const int r4  = lane >> 4;
  const int swK  = ((lane & 7) ^ r8) * 8;          // K src-col swizzle (elems)
  const int swV0 = ((lane & 15) ^ r4) * 8;         // V src-col swizzle, j even
  const int swV1 = ((lane & 15) ^ (4 + r4)) * 8;   // V src-col swizzle, j odd

  for (int t = 0; t < iters; ++t) {
    const int kvb = kv0 + t * 128;
    __syncthreads();
    // 48 dma16 chunks: 0..15 = K (16 KB), 16..47 = V (32 KB); 12 per wave.
    if (wave == 0) {
#pragma unroll
      for (int i = 0; i < 12; ++i)
        dma16(kpH + (long)(kvb + i * 8 + r8) * PDIM + swK, smem + i * 1024);
    } else if (wave == 1) {
#pragma unroll
      for (int i = 12; i < 16; ++i)
        dma16(kpH + (long)(kvb + i * 8 + r8) * PDIM + swK, smem + i * 1024);
#pragma unroll
      for (int j = 0; j < 8; ++j)
        dma16(vtH + (long)(j * 4 + r4) * NKV + kvb + ((j & 1) ? swV1 : swV0),
              smem + 16384 + j * 1024);
    } else {
      const int j0 = (wave - 2) * 12 + 8;
#pragma unroll
      for (int i = 0; i < 12; ++i) {
        const int j = j0 + i;
        dma16(vtH + (long)(j * 4 + r4) * NKV + kvb + ((j & 1) ? swV1 : swV0),
              smem + 16384 + j * 1024);
      }
    }
    __syncthreads();

#pragma unroll
    for (int s = 0; s < 4; ++s) {
      int bfr[2][2][4];   // P^T B-frags: [qsub][cl][4 x b32]
#pragma unroll
      for (int qsub = 0; qsub < 2; ++qsub) {
        // QK: S^T tile [32 kv][32 q], kv row = s*32 + l31
        f32x16 sc = {};
        const int r = s * 32 + l31;
#pragma unroll
        for (int k = 0; k < 4; ++k) {
          const int c = 2 * k + h;
          const bf16x8 a = *(const bf16x8*)(sK + r * 64 + ((c ^ (r & 7)) * 8));
          sc = __builtin_amdgcn_mfma_f32_32x32x16_bf16(a, qf[qsub][k], sc, 0, 0, 0);
        }
        // exp2 (log2-domain, fixed max 0) + pack + per-lane rsum
        int pk[4][2];
#pragma unroll
        for (int rg = 0; rg < 4; ++rg) {
          const float p0 = __builtin_amdgcn_exp2f(sc[rg * 4 + 0]);
          const float p1 = __builtin_amdgcn_exp2f(sc[rg * 4 + 1]);
          const float p2 = __builtin_amdgcn_exp2f(sc[rg * 4 + 2]);
          const float p3 = __builtin_amdgcn_exp2f(sc[rg * 4 + 3]);
          rsum[qsub] += (p0 + p1) + (p2 + p3);
          union { bf16x2 v; int i; } u0, u1;
          u0.v = bf16x2{(bf16_t)p0, (bf16_t)p1};
          u1.v = bf16x2{(bf16_t)p2, (bf16_t)p3};
          pk[rg][0] = u0.i; pk[rg][1] = u1.i;
        }
        // C-layout -> B-layout: j0-3 = half0's pk[2cl+h], j4-7 = half1's
#pragma unroll
        for (int cl = 0; cl < 2; ++cl) {
          const int e00 = __shfl_xor(pk[2 * cl][0], 32);
          const int e01 = __shfl_xor(pk[2 * cl][1], 32);
          const int e10 = __shfl_xor(pk[2 * cl + 1][0], 32);
          const int e11 = __shfl_xor(pk[2 * cl + 1][1], 32);
          bfr[qsub][cl][0] = h ? e10 : pk[2 * cl][0];
          bfr[qsub][cl][1] = h ? e11 : pk[2 * cl][1];
          bfr[qsub][cl][2] = h ? pk[2 * cl + 1][0] : e00;
          bfr[qsub][cl][3] = h ? pk[2 * cl + 1][1] : e01;
        }
      }
      // PV for this s: kv-16-block = 2s + cl, granule c = 2*(2s+cl) + h
#pragma unroll
      for (int dsub = 0; dsub < 4; ++dsub) {
        const int r = dsub * 32 + l31;
#pragma unroll
        for (int cl = 0; cl < 2; ++cl) {
          const int c = 2 * (2 * s + cl) + h;
          const bf16x8 va = *(const bf16x8*)(sV + r * 128 + ((c ^ (r & 7)) * 8));
#pragma unroll
          for (int qsub = 0; qsub < 2; ++qsub) {
            union { i32x4 i; bf16x8 v; } pb;
            pb.i = i32x4{bfr[qsub][cl][0], bfr[qsub][cl][1],
                         bfr[qsub][cl][2], bfr[qsub][cl][3]};
            o[qsub][dsub] = __builtin_amdgcn_mfma_f32_32x32x16_bf16(va, pb.v, o[qsub][dsub], 0, 0, 0);
          }
        }
      }
    }
  }

  // epilogue: transpose O^T -> row-major via wave-private LDS, store coalesced
  __syncthreads();
  bf16_t* myT = (bf16_t*)(smem + wave * 8704);   // 32 rows x 272 B (136 elems)
#pragma unroll
  for (int qsub = 0; qsub < 2; ++qsub) {
    const float lsum = rsum[qsub] + __shfl_xor(rsum[qsub], 32);
    const float scale = (splits > 1) ? 1.0f : (1.0f / lsum);
#pragma unroll
    for (int dsub = 0; dsub < 4; ++dsub)
#pragma unroll
      for (int rg = 0; rg < 4; ++rg) {
        bf16x4 w = { (bf16_t)(o[qsub][dsub][rg * 4 + 0] * scale),
                     (bf16_t)(o[qsub][dsub][rg * 4 + 1] * scale),
                     (bf16_t)(o[qsub][dsub][rg * 4 + 2] * scale),
                     (bf16_t)(o[qsub][dsub][rg * 4 + 3] * scale) };
        *(bf16x4*)(myT + l31 * 136 + dsub * 32 + rg * 8 + h * 4) = w;
      }
    const int qglob = qbase + qsub * 32;
#pragma unroll
    for (int j = 0; j < 8; ++j) {
      const int ql = j * 4 + (lane >> 4);
      bf16x8 v = *(const bf16x8*)(myT + ql * 136 + (lane & 15) * 8);
      if (splits > 1) {
        *(bf16x8*)(Opart + (((long)sp * HEADS + head) * NQ + qglob + ql) * DH + (lane & 15) * 8) = v;
      } else {
        float* op = Out + ((long)head * NQ + qglob + ql) * DH + (lane & 15) * 8;
        f32x4 a = {(float)v[0], (float)v[1], (float)v[2], (float)v[3]};
        f32x4 b = {(float)v[4], (float)v[5], (float)v[6], (float)v[7]};
        *(f32x4*)op = a; *(f32x4*)(op + 4) = b;
      }
    }
    if (splits > 1 && h == 0)
      Lpart[((long)sp * HEADS + head) * NQ + qglob + l31] = lsum;
  }
}

// ---------------------------------------------------------------------------
// combine: Out[hq][d] = (sum_s Opart[s][hq][d]) / (sum_s Lpart[s][hq])
// ---------------------------------------------------------------------------
__global__ __launch_bounds__(256) void combine_kernel(
    const bf16_t* __restrict__ Opart, const float* __restrict__ Lpart,
    float* __restrict__ Out)
{
  const long idx = (long)blockIdx.x * 256 + threadIdx.x;
  const int  d8  = (int)(idx & 15);
  const long hq  = idx >> 4;
  float l = 0.f;
  float acc[8];
#pragma unroll
  for (int j = 0; j < 8; ++j) acc[j] = 0.f;
#pragma unroll
  for (int s = 0; s < 4; ++s) {
    l += Lpart[s * (long)(HEADS * NQ) + hq];
    bf16x8 v = *(const bf16x8*)(Opart + (s * (long)(HEADS * NQ) + hq) * DH + d8 * 8);
#pragma unroll
    for (int j = 0; j < 8; ++j) acc[j] += (float)v[j];
  }
  const float inv = 1.f / l;
  f32x4 o0 = { acc[0] * inv, acc[1] * inv, acc[2] * inv, acc[3] * inv };
  f32x4 o1 = { acc[4] * inv, acc[5] * inv, acc[6] * inv, acc[7] * inv };
  float* op = Out + hq * DH + d8 * 8;
  *(f32x4*)(op)     = o0;
  *(f32x4*)(op + 4) = o1;
}

// ---------------------------------------------------------------------------
extern "C" void kernel_launch(void* const* d_in, const int* in_sizes, int n_in,
                              void* d_out, int out_size, void* d_ws, size_t ws_size,
                              hipStream_t stream)
{
  const float* Q = (const float*)d_in[0];
  const float* K = (const float*)d_in[1];
  const float* V = (const float*)d_in[2];
  const float* R = (const float*)d_in[3];
  float* Out = (float*)d_out;

  char* ws = (char*)d_ws;
  bf16_t* Qp = (bf16_t*)(ws);                          //  4 MiB: [16][2048][64]
  bf16_t* Kp = (bf16_t*)(ws + (size_t)(4  << 20));     //  8 MiB: [16][4096][64]
  bf16_t* Vt = (bf16_t*)(ws + (size_t)(12 << 20));     // 16 MiB: [16][128][4096]
  bf16_t* Opart = (bf16_t*)(ws + (size_t)(28 << 20));  // 32 MiB: [4][16][2048][128]
  float*  Lpart = (float*)(ws + (size_t)(60 << 20));   //  0.5 MiB: [4][16][2048]

  const size_t need4 = (size_t)(60 << 20) + 4ull * HEADS * NQ * sizeof(float);
  const int splits = (ws_size >= need4) ? 4 : 1;
  const int iters  = NKV / (128 * splits);

  prep_kernel<<<2560, 256, 0, stream>>>(Q, K, V, R, Qp, Kp, Vt);
  flash_kernel<<<splits * 128, 256, 0, stream>>>(Qp, Kp, Vt, Opart, Lpart, Out,
                                                 splits, iters);
  if (splits == 4)
    combine_kernel<<<2048, 256, 0, stream>>>(Opart, Lpart, Out);
}

// Round 3
// 268.923 us; speedup vs baseline: 1.3082x; 1.3082x over previous
//
#include <hip/hip_runtime.h>

#define HEADS 16
#define NQ    2048
#define NKV   4096
#define DH    128
#define PDIM  64

typedef __bf16 bf16_t;
typedef bf16_t bf16x8 __attribute__((ext_vector_type(8)));
typedef bf16_t bf16x4 __attribute__((ext_vector_type(4)));
typedef bf16_t bf16x2 __attribute__((ext_vector_type(2)));
typedef float  f32x4  __attribute__((ext_vector_type(4)));
typedef float  f32x16 __attribute__((ext_vector_type(16)));
typedef int    i32x4  __attribute__((ext_vector_type(4)));

typedef __attribute__((address_space(3))) unsigned int       lds_u32;
typedef __attribute__((address_space(1))) const unsigned int glb_u32;

__device__ __forceinline__ void dma16(const void* g, void* l) {
  __builtin_amdgcn_global_load_lds((glb_u32*)g, (lds_u32*)l, 16, 0, 0);
}

// ---------------------------------------------------------------------------
// prep: one 64x128 fp32 tile per block, staged through LDS so ALL global
// reads are 512B-contiguous per 32 lanes.
//   blocks [0,512):      Q tiles -> Qp (scaled by (1/8)*log2e)
//   blocks [512,1536):   K tiles -> Kp
//   blocks [1536,2560):  V tiles -> Vt (bf16 transpose)
// LDS tile stored with granule-level XOR swizzle (key = (row>>3)&7) so the
// V-transpose read is bank-balanced (was 8-way imbalance at stride 132*8).
// LDS: 64*128 fp32 (32 KB) + 4*16*72 bf16 (9.2 KB) = 41 KB -> 3 blocks/CU.
// ---------------------------------------------------------------------------
__global__ __launch_bounds__(256) void prep_kernel(
    const float* __restrict__ Q, const float* __restrict__ K,
    const float* __restrict__ V, const float* __restrict__ R,
    bf16_t* __restrict__ Qp, bf16_t* __restrict__ Kp, bf16_t* __restrict__ Vt)
{
  __shared__ float  sF[64 * 128];       // swizzled granules, no pad needed
  __shared__ bf16_t sY[4][16 * 72];
  const int tid = threadIdx.x;
  const int bid = blockIdx.x;

  const int isQ = (bid < 512);
  const int isK = (bid >= 512) && (bid < 1536);

  // ---- coalesced 64x128 fp32 tile load -> LDS (swizzled) ----
  const float* src;
  long row0;
  if (isQ)      { src = Q; row0 = (long)bid * 64; }
  else if (isK) { src = K; row0 = (long)(bid - 512) * 64; }
  else          { src = V; row0 = (long)(bid - 1536) * 64; }
  const float* tp = src + row0 * DH;
#pragma unroll
  for (int rep = 0; rep < 8; ++rep) {
    const int slot = tid + rep * 256;          // 2048 granules: 64 rows x 32
    const int j = slot >> 5, g = slot & 31;
    f32x4 v = *(const f32x4*)(tp + j * DH + g * 4);
    *(f32x4*)(&sF[j * 128 + ((g ^ ((j >> 3) & 7)) << 2)]) = v;
  }
  __syncthreads();

  if (!isQ && !isK) {
    // ---- V transpose path ----
    const int vb = bid - 1536;
    const int h = vb >> 6, jt = vb & 63;
    bf16_t* op = Vt + (long)h * DH * NKV + jt * 64;
#pragma unroll
    for (int rep = 0; rep < 4; ++rep) {
      const int slot = tid + rep * 256;        // 1024 slots: 128 d x 8 j-groups
      const int d = slot >> 3, j8 = (slot & 7) * 8;
      const int key = slot & 7;                // == (j>>3)&7 for j in [j8,j8+8)
      const int gsw = (((d >> 2) ^ key) << 2) + (d & 3);
      bf16x8 w;
#pragma unroll
      for (int jj = 0; jj < 8; ++jj) w[jj] = (bf16_t)sF[(j8 + jj) * 128 + gsw];
      *(bf16x8*)(op + (long)d * NKV + j8) = w;
    }
    return;
  }

  // ---- projection path (Q or K) ----
  const int wave = tid >> 6, lane = tid & 63;
  const int n16  = lane & 15, quad = lane >> 4;
  const float scale = isQ ? 0.18033688011112042f : 1.0f;   // (1/8)*log2(e)
  bf16_t* Y = isQ ? Qp : Kp;

  // B fragments from R: B[k][n], n = nt*16+n16, k = kk*32 + quad*8 + j
  bf16x8 bfr[4][4];
#pragma unroll
  for (int nt = 0; nt < 4; ++nt) {
    const int n = nt * 16 + n16;
#pragma unroll
    for (int kk = 0; kk < 4; ++kk) {
      const int k0 = kk * 32 + quad * 8;
      bf16x8 b;
#pragma unroll
      for (int j = 0; j < 8; ++j) b[j] = (bf16_t)R[(k0 + j) * PDIM + n];
      bfr[nt][kk] = b;
    }
  }

  // A fragments from the LDS tile: row = wave*16 + n16, k = kk*32 + quad*8 + j
  const int arow = wave * 16 + n16;
  const int akey = (arow >> 3) & 7;
  bf16x8 a[4];
#pragma unroll
  for (int kk = 0; kk < 4; ++kk) {
    const int k0 = kk * 32 + quad * 8;
    const int g0 = k0 >> 2;
    f32x4 x0 = *(const f32x4*)(&sF[arow * 128 + ((g0 ^ akey) << 2)]);
    f32x4 x1 = *(const f32x4*)(&sF[arow * 128 + (((g0 + 1) ^ akey) << 2)]);
    bf16x8 av;
#pragma unroll
    for (int j = 0; j < 4; ++j) { av[j] = (bf16_t)(x0[j] * scale); av[4 + j] = (bf16_t)(x1[j] * scale); }
    a[kk] = av;
  }

  bf16_t* sy = sY[wave];
#pragma unroll
  for (int nt = 0; nt < 4; ++nt) {
    f32x4 acc = {0.f, 0.f, 0.f, 0.f};
#pragma unroll
    for (int kk = 0; kk < 4; ++kk)
      acc = __builtin_amdgcn_mfma_f32_16x16x32_bf16(a[kk], bfr[nt][kk], acc, 0, 0, 0);
#pragma unroll
    for (int r = 0; r < 4; ++r)
      sy[(quad * 4 + r) * 72 + nt * 16 + n16] = (bf16_t)acc[r];
  }
  // coalesced store: lane -> (row = lane>>2, colgroup = lane&3)
  const long xrow = row0 + wave * 16;
  const int row = lane >> 2, cg = lane & 3;
  bf16x8 w0 = *(const bf16x8*)(&sy[row * 72 + cg * 16]);
  bf16x8 w1 = *(const bf16x8*)(&sy[row * 72 + cg * 16 + 8]);
  *(bf16x8*)(Y + (xrow + row) * PDIM + cg * 16)     = w0;
  *(bf16x8*)(Y + (xrow + row) * PDIM + cg * 16 + 8) = w1;
}

// ---------------------------------------------------------------------------
// flash v8 = EXACT round-0 v4 body (proven 71.2 us; r1/r2 showed any
// structural perturbation — issue-early DMA, KVB=128 unroll — spills the
// f32x16 accumulators to scratch: FETCH/WRITE blow up ~10x). Register-
// neutral changes only:
//   * s_setprio(1)/(0) around the QK and PV MFMA clusters (T5; blocks are
//     desynced so waves are at different phases — m191 regime).
//   * splits widened to 8 when workspace allows (grid 2048): LDS 24.6 KB
//     admits 6 blocks/CU; if VGPR permits 3 waves/SIMD this lifts
//     occupancy 25% -> 37% to hide the per-iter barrier drain.
// ---------------------------------------------------------------------------
__global__ __launch_bounds__(128, 2) void flash_kernel(
    const bf16_t* __restrict__ Qp, const bf16_t* __restrict__ Kp,
    const bf16_t* __restrict__ Vt, bf16_t* __restrict__ Opart,
    float* __restrict__ Lpart, float* __restrict__ Out,
    int splits, int iters)
{
  __shared__ char smem[24576];
  bf16_t* sK = (bf16_t*)smem;            // 64 rows x 64, swizzled chunks (8 KB)
  bf16_t* sV = (bf16_t*)(smem + 8192);   // 128 rows x 64, swizzled (16 KB)

  const int tid  = threadIdx.x;
  const int wave = tid >> 6, lane = tid & 63;
  const int l31  = lane & 31, h = lane >> 5;

  const int head = blockIdx.x & 15;      // XCD round-robin -> 2 heads/XCD
  const int qt   = (blockIdx.x >> 4) & 15;
  const int sp   = blockIdx.x >> 8;

  const int qbase = qt * 128 + wave * 64;
  const int kv0   = sp * (64 * iters);

  // persistent Q B-frags: B[k=p][n=q], q = qsub*32+l31, p = k*16 + 8h + j
  bf16x8 qf[2][4];
#pragma unroll
  for (int qsub = 0; qsub < 2; ++qsub)
#pragma unroll
    for (int k = 0; k < 4; ++k)
      qf[qsub][k] = *(const bf16x8*)(Qp + ((long)head * NQ + qbase + qsub * 32 + l31) * PDIM
                                     + k * 16 + h * 8);

  f32x16 o[2][4] = {};          // O^T accum: [qsub][dsub], C layout
  float rsum[2] = {0.f, 0.f};   // per-lane partial row sums

  const bf16_t* kpH = Kp + (long)head * NKV * PDIM;
  const bf16_t* vtH = Vt + (long)head * DH * NKV;

  const int sw = ((lane & 7) ^ ((lane >> 3) & 7)) * 8;  // src-col swizzle (elems)
  const int r8 = lane >> 3;                             // row within 8-row group

  for (int t = 0; t < iters; ++t) {
    const int kvb = kv0 + t * 64;
    __syncthreads();
    if (wave == 0) {
#pragma unroll
      for (int i = 0; i < 8; ++i)
        dma16(kpH + (long)(kvb + i * 8 + r8) * PDIM + sw, smem + i * 1024);
#pragma unroll
      for (int i = 0; i < 4; ++i)
        dma16(vtH + (long)(i * 8 + r8) * NKV + kvb + sw, smem + 8192 + i * 1024);
    } else {
#pragma unroll
      for (int i = 4; i < 16; ++i)
        dma16(vtH + (long)(i * 8 + r8) * NKV + kvb + sw, smem + 8192 + i * 1024);
    }
    __syncthreads();

#pragma unroll
    for (int s = 0; s < 2; ++s) {
      int bfr[2][2][4];   // P^T B-frags: [qsub][cl][4 x b32]
#pragma unroll
      for (int qsub = 0; qsub < 2; ++qsub) {
        // QK: S^T tile [32 kv][32 q], kv row = s*32 + l31
        f32x16 sc = {};
        const int r = s * 32 + l31;
        __builtin_amdgcn_s_setprio(1);
#pragma unroll
        for (int k = 0; k < 4; ++k) {
          const int c = 2 * k + h;
          const bf16x8 a = *(const bf16x8*)(sK + r * 64 + ((c ^ (r & 7)) * 8));
          sc = __builtin_amdgcn_mfma_f32_32x32x16_bf16(a, qf[qsub][k], sc, 0, 0, 0);
        }
        __builtin_amdgcn_s_setprio(0);
        // exp2 (log2-domain, fixed max 0) + pack + per-lane rsum
        int pk[4][2];
#pragma unroll
        for (int rg = 0; rg < 4; ++rg) {
          const float p0 = __builtin_amdgcn_exp2f(sc[rg * 4 + 0]);
          const float p1 = __builtin_amdgcn_exp2f(sc[rg * 4 + 1]);
          const float p2 = __builtin_amdgcn_exp2f(sc[rg * 4 + 2]);
          const float p3 = __builtin_amdgcn_exp2f(sc[rg * 4 + 3]);
          rsum[qsub] += (p0 + p1) + (p2 + p3);
          union { bf16x2 v; int i; } u0, u1;
          u0.v = bf16x2{(bf16_t)p0, (bf16_t)p1};
          u1.v = bf16x2{(bf16_t)p2, (bf16_t)p3};
          pk[rg][0] = u0.i; pk[rg][1] = u1.i;
        }
        // C-layout -> B-layout: j0-3 = half0's pk[2cl+h], j4-7 = half1's
#pragma unroll
        for (int cl = 0; cl < 2; ++cl) {
          const int e00 = __shfl_xor(pk[2 * cl][0], 32);
          const int e01 = __shfl_xor(pk[2 * cl][1], 32);
          const int e10 = __shfl_xor(pk[2 * cl + 1][0], 32);
          const int e11 = __shfl_xor(pk[2 * cl + 1][1], 32);
          bfr[qsub][cl][0] = h ? e10 : pk[2 * cl][0];
          bfr[qsub][cl][1] = h ? e11 : pk[2 * cl][1];
          bfr[qsub][cl][2] = h ? pk[2 * cl + 1][0] : e00;
          bfr[qsub][cl][3] = h ? pk[2 * cl + 1][1] : e01;
        }
      }
      // PV for this s: kv steps c = 2s + cl
      __builtin_amdgcn_s_setprio(1);
#pragma unroll
      for (int dsub = 0; dsub < 4; ++dsub) {
        const int r = dsub * 32 + l31;
#pragma unroll
        for (int cl = 0; cl < 2; ++cl) {
          const int c = 2 * (2 * s + cl) + h;
          const bf16x8 va = *(const bf16x8*)(sV + r * 64 + ((c ^ (r & 7)) * 8));
#pragma unroll
          for (int qsub = 0; qsub < 2; ++qsub) {
            union { i32x4 i; bf16x8 v; } pb;
            pb.i = i32x4{bfr[qsub][cl][0], bfr[qsub][cl][1],
                         bfr[qsub][cl][2], bfr[qsub][cl][3]};
            o[qsub][dsub] = __builtin_amdgcn_mfma_f32_32x32x16_bf16(va, pb.v, o[qsub][dsub], 0, 0, 0);
          }
        }
      }
      __builtin_amdgcn_s_setprio(0);
    }
  }

  // epilogue: transpose O^T -> row-major via wave-private LDS, store coalesced
  __syncthreads();
  bf16_t* myT = (bf16_t*)(smem + wave * 8704);   // 32 rows x 272 B (136 elems)
#pragma unroll
  for (int qsub = 0; qsub < 2; ++qsub) {
    const float lsum = rsum[qsub] + __shfl_xor(rsum[qsub], 32);
    const float scale = (splits > 1) ? 1.0f : (1.0f / lsum);
#pragma unroll
    for (int dsub = 0; dsub < 4; ++dsub)
#pragma unroll
      for (int rg = 0; rg < 4; ++rg) {
        bf16x4 w = { (bf16_t)(o[qsub][dsub][rg * 4 + 0] * scale),
                     (bf16_t)(o[qsub][dsub][rg * 4 + 1] * scale),
                     (bf16_t)(o[qsub][dsub][rg * 4 + 2] * scale),
                     (bf16_t)(o[qsub][dsub][rg * 4 + 3] * scale) };
        *(bf16x4*)(myT + l31 * 136 + dsub * 32 + rg * 8 + h * 4) = w;
      }
    const int qglob = qbase + qsub * 32;
#pragma unroll
    for (int j = 0; j < 8; ++j) {
      const int ql = j * 4 + (lane >> 4);
      bf16x8 v = *(const bf16x8*)(myT + ql * 136 + (lane & 15) * 8);
      if (splits > 1) {
        *(bf16x8*)(Opart + (((long)sp * HEADS + head) * NQ + qglob + ql) * DH + (lane & 15) * 8) = v;
      } else {
        float* op = Out + ((long)head * NQ + qglob + ql) * DH + (lane & 15) * 8;
        f32x4 a = {(float)v[0], (float)v[1], (float)v[2], (float)v[3]};
        f32x4 b = {(float)v[4], (float)v[5], (float)v[6], (float)v[7]};
        *(f32x4*)op = a; *(f32x4*)(op + 4) = b;
      }
    }
    if (splits > 1 && h == 0)
      Lpart[((long)sp * HEADS + head) * NQ + qglob + l31] = lsum;
  }
}

// ---------------------------------------------------------------------------
// combine: Out[hq][d] = (sum_s Opart[s][hq][d]) / (sum_s Lpart[s][hq])
// ---------------------------------------------------------------------------
__global__ __launch_bounds__(256) void combine_kernel(
    const bf16_t* __restrict__ Opart, const float* __restrict__ Lpart,
    float* __restrict__ Out, int splits)
{
  const long idx = (long)blockIdx.x * 256 + threadIdx.x;
  const int  d8  = (int)(idx & 15);
  const long hq  = idx >> 4;
  float l = 0.f;
  float acc[8];
#pragma unroll
  for (int j = 0; j < 8; ++j) acc[j] = 0.f;
  for (int s = 0; s < splits; ++s) {
    l += Lpart[s * (long)(HEADS * NQ) + hq];
    bf16x8 v = *(const bf16x8*)(Opart + (s * (long)(HEADS * NQ) + hq) * DH + d8 * 8);
#pragma unroll
    for (int j = 0; j < 8; ++j) acc[j] += (float)v[j];
  }
  const float inv = 1.f / l;
  f32x4 o0 = { acc[0] * inv, acc[1] * inv, acc[2] * inv, acc[3] * inv };
  f32x4 o1 = { acc[4] * inv, acc[5] * inv, acc[6] * inv, acc[7] * inv };
  float* op = Out + hq * DH + d8 * 8;
  *(f32x4*)(op)     = o0;
  *(f32x4*)(op + 4) = o1;
}

// ---------------------------------------------------------------------------
extern "C" void kernel_launch(void* const* d_in, const int* in_sizes, int n_in,
                              void* d_out, int out_size, void* d_ws, size_t ws_size,
                              hipStream_t stream)
{
  const float* Q = (const float*)d_in[0];
  const float* K = (const float*)d_in[1];
  const float* V = (const float*)d_in[2];
  const float* R = (const float*)d_in[3];
  float* Out = (float*)d_out;

  char* ws = (char*)d_ws;
  bf16_t* Qp = (bf16_t*)(ws);                          //  4 MiB: [16][2048][64]
  bf16_t* Kp = (bf16_t*)(ws + (size_t)(4  << 20));     //  8 MiB: [16][4096][64]
  bf16_t* Vt = (bf16_t*)(ws + (size_t)(12 << 20));     // 16 MiB: [16][128][4096]

  const size_t base   = (size_t)28 << 20;              // Opart offset
  const size_t oBytes = (size_t)HEADS * NQ * DH * 2;   // 8 MiB per split
  const size_t lBytes = (size_t)HEADS * NQ * 4;        // 128 KiB per split
  int splits = 1;
  if (ws_size >= base + 8 * (oBytes + lBytes))      splits = 8;
  else if (ws_size >= base + 4 * (oBytes + lBytes)) splits = 4;

  bf16_t* Opart = (bf16_t*)(ws + base);
  float*  Lpart = (float*)(ws + base + (size_t)splits * oBytes);
  const int iters = NKV / (64 * splits);

  prep_kernel<<<2560, 256, 0, stream>>>(Q, K, V, R, Qp, Kp, Vt);
  flash_kernel<<<splits * 256, 128, 0, stream>>>(Qp, Kp, Vt, Opart, Lpart, Out,
                                                 splits, iters);
  if (splits > 1)
    combine_kernel<<<2048, 256, 0, stream>>>(Opart, Lpart, Out, splits);
}

// Round 4
// 205.230 us; speedup vs baseline: 1.7143x; 1.3103x over previous
//
#include <hip/hip_runtime.h>

#define HEADS 16
#define NQ    2048
#define NKV   4096
#define DH    128
#define PDIM  64

typedef __bf16 bf16_t;
typedef bf16_t bf16x8 __attribute__((ext_vector_type(8)));
typedef bf16_t bf16x4 __attribute__((ext_vector_type(4)));
typedef bf16_t bf16x2 __attribute__((ext_vector_type(2)));
typedef float  f32x4  __attribute__((ext_vector_type(4)));
typedef float  f32x16 __attribute__((ext_vector_type(16)));
typedef int    i32x4  __attribute__((ext_vector_type(4)));

typedef __attribute__((address_space(3))) unsigned int       lds_u32;
typedef __attribute__((address_space(1))) const unsigned int glb_u32;

__device__ __forceinline__ void dma16(const void* g, void* l) {
  __builtin_amdgcn_global_load_lds((glb_u32*)g, (lds_u32*)l, 16, 0, 0);
}

// ---------------------------------------------------------------------------
// rprep: one-time R -> bf16 transpose, Rbt[n][k] (64 x 128, 16 KB).
// All 1536 proj blocks then read B-frags as vector bf16x8 loads from this
// L2-resident table instead of 128 scalar f32 loads each.
// ---------------------------------------------------------------------------
__global__ __launch_bounds__(256) void rprep_kernel(
    const float* __restrict__ R, bf16_t* __restrict__ Rbt)
{
  const int tid = threadIdx.x;
#pragma unroll
  for (int rep = 0; rep < 32; ++rep) {
    const int idx = tid + rep * 256;           // 8192 elems
    const int n = idx & 63, k = idx >> 6;
    Rbt[n * 128 + k] = (bf16_t)R[k * 64 + n];  // coalesced read, tiny scatter
  }
}

// ---------------------------------------------------------------------------
// proj: Y = X * R (X = Q scaled, or K), 64 rows per block, MFMA 16x16x32.
//   * A-frags straight from global (lane reads 2 x f32x4 = 32B contiguous;
//     a wave covers 16 rows x 128B segments) — no LDS staging tile.
//   * B-frags from Rbt as bf16x8 vector loads (16/thread, L2-hit).
//   * LDS only for the 9 KB sY store-transpose -> much higher occupancy
//     than the old 41 KB prep block.
// blocks [0,512): Q -> Qp (scaled by (1/8)*log2e); [512,1536): K -> Kp.
// ---------------------------------------------------------------------------
__global__ __launch_bounds__(256) void proj_kernel(
    const float* __restrict__ Q, const float* __restrict__ K,
    const bf16_t* __restrict__ Rbt,
    bf16_t* __restrict__ Qp, bf16_t* __restrict__ Kp)
{
  __shared__ bf16_t sY[4][16 * 72];
  const int tid = threadIdx.x;
  const int bid = blockIdx.x;

  const int isQ = (bid < 512);
  const float* src = isQ ? Q : K;
  const long row0  = isQ ? (long)bid * 64 : (long)(bid - 512) * 64;
  const float scale = isQ ? 0.18033688011112042f : 1.0f;   // (1/8)*log2(e)
  bf16_t* Y = isQ ? Qp : Kp;

  const int wave = tid >> 6, lane = tid & 63;
  const int n16  = lane & 15, quad = lane >> 4;

  // B fragments: B[k][n], n = nt*16+n16, k = kk*32 + quad*8 + j
  bf16x8 bfr[4][4];
#pragma unroll
  for (int nt = 0; nt < 4; ++nt)
#pragma unroll
    for (int kk = 0; kk < 4; ++kk)
      bfr[nt][kk] = *(const bf16x8*)(Rbt + (nt * 16 + n16) * 128 + kk * 32 + quad * 8);

  // A fragments: row = wave*16 + n16, k = kk*32 + quad*8 + j, direct global
  const int arow = wave * 16 + n16;
  const float* xp = src + (row0 + arow) * DH;
  bf16x8 a[4];
#pragma unroll
  for (int kk = 0; kk < 4; ++kk) {
    const int k0 = kk * 32 + quad * 8;
    f32x4 x0 = *(const f32x4*)(xp + k0);
    f32x4 x1 = *(const f32x4*)(xp + k0 + 4);
    bf16x8 av;
#pragma unroll
    for (int j = 0; j < 4; ++j) { av[j] = (bf16_t)(x0[j] * scale); av[4 + j] = (bf16_t)(x1[j] * scale); }
    a[kk] = av;
  }

  bf16_t* sy = sY[wave];
#pragma unroll
  for (int nt = 0; nt < 4; ++nt) {
    f32x4 acc = {0.f, 0.f, 0.f, 0.f};
#pragma unroll
    for (int kk = 0; kk < 4; ++kk)
      acc = __builtin_amdgcn_mfma_f32_16x16x32_bf16(a[kk], bfr[nt][kk], acc, 0, 0, 0);
#pragma unroll
    for (int r = 0; r < 4; ++r)
      sy[(quad * 4 + r) * 72 + nt * 16 + n16] = (bf16_t)acc[r];
  }
  // coalesced store: lane -> (row = lane>>2, colgroup = lane&3)
  const long xrow = row0 + wave * 16;
  const int row = lane >> 2, cg = lane & 3;
  bf16x8 w0 = *(const bf16x8*)(&sy[row * 72 + cg * 16]);
  bf16x8 w1 = *(const bf16x8*)(&sy[row * 72 + cg * 16 + 8]);
  *(bf16x8*)(Y + (xrow + row) * PDIM + cg * 16)     = w0;
  *(bf16x8*)(Y + (xrow + row) * PDIM + cg * 16 + 8) = w1;
}

// ---------------------------------------------------------------------------
// vtrans: V (64x128 f32 tile) -> Vt (bf16, transposed). Tile staged in LDS
// with granule-level XOR swizzle (key = (row>>3)&7) so the transpose read
// is bank-balanced. LDS 32 KB -> 5 blocks/CU.
// ---------------------------------------------------------------------------
__global__ __launch_bounds__(256) void vtrans_kernel(
    const float* __restrict__ V, bf16_t* __restrict__ Vt)
{
  __shared__ float sF[64 * 128];
  const int tid = threadIdx.x;
  const int bid = blockIdx.x;

  const float* tp = V + (long)bid * 64 * DH;
#pragma unroll
  for (int rep = 0; rep < 8; ++rep) {
    const int slot = tid + rep * 256;          // 2048 granules: 64 rows x 32
    const int j = slot >> 5, g = slot & 31;
    f32x4 v = *(const f32x4*)(tp + j * DH + g * 4);
    *(f32x4*)(&sF[j * 128 + ((g ^ ((j >> 3) & 7)) << 2)]) = v;
  }
  __syncthreads();

  const int h = bid >> 6, jt = bid & 63;
  bf16_t* op = Vt + (long)h * DH * NKV + jt * 64;
#pragma unroll
  for (int rep = 0; rep < 4; ++rep) {
    const int slot = tid + rep * 256;          // 1024 slots: 128 d x 8 j-groups
    const int d = slot >> 3, j8 = (slot & 7) * 8;
    const int key = slot & 7;                  // == (j>>3)&7 for j in [j8,j8+8)
    const int gsw = (((d >> 2) ^ key) << 2) + (d & 3);
    bf16x8 w;
#pragma unroll
    for (int jj = 0; jj < 8; ++jj) w[jj] = (bf16_t)sF[(j8 + jj) * 128 + gsw];
    *(bf16x8*)(op + (long)d * NKV + j8) = w;
  }
}

// ---------------------------------------------------------------------------
// flash v4 — BYTE-IDENTICAL to the round-0 source (proven 71.2 us).
// r1-r3 showed ANY source perturbation (issue-early DMA, KVB=128, even
// setprio insertion) tips regalloc into spilling the f32x16 accumulators
// (FETCH/WRITE inflate 5-10x). Do not touch this kernel.
// ---------------------------------------------------------------------------
__global__ __launch_bounds__(128, 2) void flash_kernel(
    const bf16_t* __restrict__ Qp, const bf16_t* __restrict__ Kp,
    const bf16_t* __restrict__ Vt, bf16_t* __restrict__ Opart,
    float* __restrict__ Lpart, float* __restrict__ Out,
    int splits, int iters)
{
  __shared__ char smem[24576];
  bf16_t* sK = (bf16_t*)smem;            // 64 rows x 64, swizzled chunks (8 KB)
  bf16_t* sV = (bf16_t*)(smem + 8192);   // 128 rows x 64, swizzled (16 KB)

  const int tid  = threadIdx.x;
  const int wave = tid >> 6, lane = tid & 63;
  const int l31  = lane & 31, h = lane >> 5;

  const int head = blockIdx.x & 15;      // XCD round-robin -> 2 heads/XCD
  const int qt   = (blockIdx.x >> 4) & 15;
  const int sp   = blockIdx.x >> 8;

  const int qbase = qt * 128 + wave * 64;
  const int kv0   = sp * (64 * iters);

  // persistent Q B-frags: B[k=p][n=q], q = qsub*32+l31, p = k*16 + 8h + j
  bf16x8 qf[2][4];
#pragma unroll
  for (int qsub = 0; qsub < 2; ++qsub)
#pragma unroll
    for (int k = 0; k < 4; ++k)
      qf[qsub][k] = *(const bf16x8*)(Qp + ((long)head * NQ + qbase + qsub * 32 + l31) * PDIM
                                     + k * 16 + h * 8);

  f32x16 o[2][4] = {};          // O^T accum: [qsub][dsub], C layout
  float rsum[2] = {0.f, 0.f};   // per-lane partial row sums

  const bf16_t* kpH = Kp + (long)head * NKV * PDIM;
  const bf16_t* vtH = Vt + (long)head * DH * NKV;

  const int sw = ((lane & 7) ^ ((lane >> 3) & 7)) * 8;  // src-col swizzle (elems)
  const int r8 = lane >> 3;                             // row within 8-row group

  for (int t = 0; t < iters; ++t) {
    const int kvb = kv0 + t * 64;
    __syncthreads();
    if (wave == 0) {
#pragma unroll
      for (int i = 0; i < 8; ++i)
        dma16(kpH + (long)(kvb + i * 8 + r8) * PDIM + sw, smem + i * 1024);
#pragma unroll
      for (int i = 0; i < 4; ++i)
        dma16(vtH + (long)(i * 8 + r8) * NKV + kvb + sw, smem + 8192 + i * 1024);
    } else {
#pragma unroll
      for (int i = 4; i < 16; ++i)
        dma16(vtH + (long)(i * 8 + r8) * NKV + kvb + sw, smem + 8192 + i * 1024);
    }
    __syncthreads();

#pragma unroll
    for (int s = 0; s < 2; ++s) {
      int bfr[2][2][4];   // P^T B-frags: [qsub][cl][4 x b32]
#pragma unroll
      for (int qsub = 0; qsub < 2; ++qsub) {
        // QK: S^T tile [32 kv][32 q], kv row = s*32 + l31
        f32x16 sc = {};
        const int r = s * 32 + l31;
#pragma unroll
        for (int k = 0; k < 4; ++k) {
          const int c = 2 * k + h;
          const bf16x8 a = *(const bf16x8*)(sK + r * 64 + ((c ^ (r & 7)) * 8));
          sc = __builtin_amdgcn_mfma_f32_32x32x16_bf16(a, qf[qsub][k], sc, 0, 0, 0);
        }
        // exp2 (log2-domain, fixed max 0) + pack + per-lane rsum
        int pk[4][2];
#pragma unroll
        for (int rg = 0; rg < 4; ++rg) {
          const float p0 = __builtin_amdgcn_exp2f(sc[rg * 4 + 0]);
          const float p1 = __builtin_amdgcn_exp2f(sc[rg * 4 + 1]);
          const float p2 = __builtin_amdgcn_exp2f(sc[rg * 4 + 2]);
          const float p3 = __builtin_amdgcn_exp2f(sc[rg * 4 + 3]);
          rsum[qsub] += (p0 + p1) + (p2 + p3);
          union { bf16x2 v; int i; } u0, u1;
          u0.v = bf16x2{(bf16_t)p0, (bf16_t)p1};
          u1.v = bf16x2{(bf16_t)p2, (bf16_t)p3};
          pk[rg][0] = u0.i; pk[rg][1] = u1.i;
        }
        // C-layout -> B-layout: j0-3 = half0's pk[2cl+h], j4-7 = half1's
#pragma unroll
        for (int cl = 0; cl < 2; ++cl) {
          const int e00 = __shfl_xor(pk[2 * cl][0], 32);
          const int e01 = __shfl_xor(pk[2 * cl][1], 32);
          const int e10 = __shfl_xor(pk[2 * cl + 1][0], 32);
          const int e11 = __shfl_xor(pk[2 * cl + 1][1], 32);
          bfr[qsub][cl][0] = h ? e10 : pk[2 * cl][0];
          bfr[qsub][cl][1] = h ? e11 : pk[2 * cl][1];
          bfr[qsub][cl][2] = h ? pk[2 * cl + 1][0] : e00;
          bfr[qsub][cl][3] = h ? pk[2 * cl + 1][1] : e01;
        }
      }
      // PV for this s: kv steps c = 2s + cl
#pragma unroll
      for (int dsub = 0; dsub < 4; ++dsub) {
        const int r = dsub * 32 + l31;
#pragma unroll
        for (int cl = 0; cl < 2; ++cl) {
          const int c = 2 * (2 * s + cl) + h;
          const bf16x8 va = *(const bf16x8*)(sV + r * 64 + ((c ^ (r & 7)) * 8));
#pragma unroll
          for (int qsub = 0; qsub < 2; ++qsub) {
            union { i32x4 i; bf16x8 v; } pb;
            pb.i = i32x4{bfr[qsub][cl][0], bfr[qsub][cl][1],
                         bfr[qsub][cl][2], bfr[qsub][cl][3]};
            o[qsub][dsub] = __builtin_amdgcn_mfma_f32_32x32x16_bf16(va, pb.v, o[qsub][dsub], 0, 0, 0);
          }
        }
      }
    }
  }

  // epilogue: transpose O^T -> row-major via wave-private LDS, store coalesced
  __syncthreads();
  bf16_t* myT = (bf16_t*)(smem + wave * 8704);   // 32 rows x 272 B (136 elems)
#pragma unroll
  for (int qsub = 0; qsub < 2; ++qsub) {
    const float lsum = rsum[qsub] + __shfl_xor(rsum[qsub], 32);
    const float scale = (splits > 1) ? 1.0f : (1.0f / lsum);
#pragma unroll
    for (int dsub = 0; dsub < 4; ++dsub)
#pragma unroll
      for (int rg = 0; rg < 4; ++rg) {
        bf16x4 w = { (bf16_t)(o[qsub][dsub][rg * 4 + 0] * scale),
                     (bf16_t)(o[qsub][dsub][rg * 4 + 1] * scale),
                     (bf16_t)(o[qsub][dsub][rg * 4 + 2] * scale),
                     (bf16_t)(o[qsub][dsub][rg * 4 + 3] * scale) };
        *(bf16x4*)(myT + l31 * 136 + dsub * 32 + rg * 8 + h * 4) = w;
      }
    const int qglob = qbase + qsub * 32;
#pragma unroll
    for (int j = 0; j < 8; ++j) {
      const int ql = j * 4 + (lane >> 4);
      bf16x8 v = *(const bf16x8*)(myT + ql * 136 + (lane & 15) * 8);
      if (splits > 1) {
        *(bf16x8*)(Opart + (((long)sp * HEADS + head) * NQ + qglob + ql) * DH + (lane & 15) * 8) = v;
      } else {
        float* op = Out + ((long)head * NQ + qglob + ql) * DH + (lane & 15) * 8;
        f32x4 a = {(float)v[0], (float)v[1], (float)v[2], (float)v[3]};
        f32x4 b = {(float)v[4], (float)v[5], (float)v[6], (float)v[7]};
        *(f32x4*)op = a; *(f32x4*)(op + 4) = b;
      }
    }
    if (splits > 1 && h == 0)
      Lpart[((long)sp * HEADS + head) * NQ + qglob + l31] = lsum;
  }
}

// ---------------------------------------------------------------------------
// combine: Out[hq][d] = (sum_s Opart[s][hq][d]) / (sum_s Lpart[s][hq])
// (round-0 form, fixed 4 splits)
// ---------------------------------------------------------------------------
__global__ __launch_bounds__(256) void combine_kernel(
    const bf16_t* __restrict__ Opart, const float* __restrict__ Lpart,
    float* __restrict__ Out)
{
  const long idx = (long)blockIdx.x * 256 + threadIdx.x;
  const int  d8  = (int)(idx & 15);
  const long hq  = idx >> 4;
  float l = 0.f;
  float acc[8];
#pragma unroll
  for (int j = 0; j < 8; ++j) acc[j] = 0.f;
#pragma unroll
  for (int s = 0; s < 4; ++s) {
    l += Lpart[s * (long)(HEADS * NQ) + hq];
    bf16x8 v = *(const bf16x8*)(Opart + (s * (long)(HEADS * NQ) + hq) * DH + d8 * 8);
#pragma unroll
    for (int j = 0; j < 8; ++j) acc[j] += (float)v[j];
  }
  const float inv = 1.f / l;
  f32x4 o0 = { acc[0] * inv, acc[1] * inv, acc[2] * inv, acc[3] * inv };
  f32x4 o1 = { acc[4] * inv, acc[5] * inv, acc[6] * inv, acc[7] * inv };
  float* op = Out + hq * DH + d8 * 8;
  *(f32x4*)(op)     = o0;
  *(f32x4*)(op + 4) = o1;
}

// ---------------------------------------------------------------------------
extern "C" void kernel_launch(void* const* d_in, const int* in_sizes, int n_in,
                              void* d_out, int out_size, void* d_ws, size_t ws_size,
                              hipStream_t stream)
{
  const float* Q = (const float*)d_in[0];
  const float* K = (const float*)d_in[1];
  const float* V = (const float*)d_in[2];
  const float* R = (const float*)d_in[3];
  float* Out = (float*)d_out;

  char* ws = (char*)d_ws;
  bf16_t* Qp = (bf16_t*)(ws);                          //  4 MiB: [16][2048][64]
  bf16_t* Kp = (bf16_t*)(ws + (size_t)(4  << 20));     //  8 MiB: [16][4096][64]
  bf16_t* Vt = (bf16_t*)(ws + (size_t)(12 << 20));     // 16 MiB: [16][128][4096]
  bf16_t* Opart = (bf16_t*)(ws + (size_t)(28 << 20));  // 32 MiB: [4][16][2048][128]
  float*  Lpart = (float*)(ws + (size_t)(60 << 20));   //  0.5 MiB: [4][16][2048]
  // Rbt (16 KB) overlaps Opart's first bytes: written by rprep, read by
  // proj, and only AFTER proj completes does flash write Opart (stream-
  // ordered) -> lifetimes are disjoint, zero extra workspace needed.
  bf16_t* Rbt = (bf16_t*)(ws + (size_t)(28 << 20));

  const size_t need4 = (size_t)(60 << 20) + 4ull * HEADS * NQ * sizeof(float);
  const int splits = (ws_size >= need4) ? 4 : 1;
  const int iters  = NKV / (64 * splits);

  rprep_kernel<<<1, 256, 0, stream>>>(R, Rbt);
  proj_kernel<<<1536, 256, 0, stream>>>(Q, K, Rbt, Qp, Kp);
  vtrans_kernel<<<1024, 256, 0, stream>>>(V, Vt);
  flash_kernel<<<splits * 256, 128, 0, stream>>>(Qp, Kp, Vt, Opart, Lpart, Out,
                                                 splits, iters);
  if (splits == 4)
    combine_kernel<<<2048, 256, 0, stream>>>(Opart, Lpart, Out);
}

// Round 6
// 194.078 us; speedup vs baseline: 1.8128x; 1.0575x over previous
//
#include <hip/hip_runtime.h>

#define HEADS 16
#define NQ    2048
#define NKV   4096
#define DH    128
#define PDIM  64

typedef __bf16 bf16_t;
typedef bf16_t bf16x8 __attribute__((ext_vector_type(8)));
typedef bf16_t bf16x4 __attribute__((ext_vector_type(4)));
typedef bf16_t bf16x2 __attribute__((ext_vector_type(2)));
typedef float  f32x4  __attribute__((ext_vector_type(4)));
typedef float  f32x16 __attribute__((ext_vector_type(16)));
typedef int    i32x4  __attribute__((ext_vector_type(4)));

typedef __attribute__((address_space(3))) unsigned int       lds_u32;
typedef __attribute__((address_space(1))) const unsigned int glb_u32;

__device__ __forceinline__ void dma16(const void* g, void* l) {
  __builtin_amdgcn_global_load_lds((glb_u32*)g, (lds_u32*)l, 16, 0, 0);
}

// ---------------------------------------------------------------------------
// prep (merged, 3-launch pipeline restored — r4 showed +2 launches cost
// ~11 us total while the split bought nothing):
//   blocks [0,512):      Q -> Qp (scaled by (1/8)*log2e)   [proj path]
//   blocks [512,1536):   K -> Kp                            [proj path]
//   blocks [1536,2560):  V -> Vt (bf16 transpose)           [vtrans path]
// proj path (r4-improved, now self-contained):
//   * R transposed to bf16 in LDS per block: 32 coalesced f32 loads/thread
//     (replaces r0's 128 scalar global loads/thread), padded rows [64][136].
//   * A-frags direct from global (32B contiguous per lane) — no staging tile.
//   * LDS 17.4 KB sR + 9.2 KB sY.
// vtrans path: r2's granule-XOR-swizzled transpose (bank-balanced), 32 KB.
// ---------------------------------------------------------------------------
__global__ __launch_bounds__(256) void prep_kernel(
    const float* __restrict__ Q, const float* __restrict__ K,
    const float* __restrict__ V, const float* __restrict__ R,
    bf16_t* __restrict__ Qp, bf16_t* __restrict__ Kp, bf16_t* __restrict__ Vt)
{
  __shared__ char lds[32768];
  const int tid = threadIdx.x;
  const int bid = blockIdx.x;

  if (bid >= 1536) {
    // ---- V transpose path ----
    float* sF = (float*)lds;                   // 64 x 128 f32, granule-swizzled
    const int vb = bid - 1536;
    const float* tp = V + (long)vb * 64 * DH;
#pragma unroll
    for (int rep = 0; rep < 8; ++rep) {
      const int slot = tid + rep * 256;        // 2048 granules: 64 rows x 32
      const int j = slot >> 5, g = slot & 31;
      f32x4 v = *(const f32x4*)(tp + j * DH + g * 4);
      *(f32x4*)(&sF[j * 128 + ((g ^ ((j >> 3) & 7)) << 2)]) = v;
    }
    __syncthreads();

    const int h = vb >> 6, jt = vb & 63;
    bf16_t* op = Vt + (long)h * DH * NKV + jt * 64;
#pragma unroll
    for (int rep = 0; rep < 4; ++rep) {
      const int slot = tid + rep * 256;        // 1024 slots: 128 d x 8 j-groups
      const int d = slot >> 3, j8 = (slot & 7) * 8;
      const int key = slot & 7;                // == (j>>3)&7 for j in [j8,j8+8)
      const int gsw = (((d >> 2) ^ key) << 2) + (d & 3);
      bf16x8 w;
#pragma unroll
      for (int jj = 0; jj < 8; ++jj) w[jj] = (bf16_t)sF[(j8 + jj) * 128 + gsw];
      *(bf16x8*)(op + (long)d * NKV + j8) = w;
    }
    return;
  }

  // ---- projection path (Q or K) ----
  bf16_t* sR = (bf16_t*)lds;                   // [64][136] bf16 (17.4 KB)
  bf16_t* sYb = (bf16_t*)(lds + 64 * 136 * 2); // 4 x [16*72] bf16 (9.2 KB)

  const int isQ = (bid < 512);
  const float* src = isQ ? Q : K;
  const long row0  = isQ ? (long)bid * 64 : (long)(bid - 512) * 64;
  const float scale = isQ ? 0.18033688011112042f : 1.0f;   // (1/8)*log2(e)
  bf16_t* Y = isQ ? Qp : Kp;

  // R -> LDS transpose: sR[n][k] = R[k][n]; reads R linearly (coalesced).
#pragma unroll
  for (int rep = 0; rep < 32; ++rep) {
    const int idx = tid + rep * 256;           // 8192 elems, k = idx>>6, n low
    sR[(idx & 63) * 136 + (idx >> 6)] = (bf16_t)R[idx];
  }
  __syncthreads();

  const int wave = tid >> 6, lane = tid & 63;
  const int n16  = lane & 15, quad = lane >> 4;

  // B fragments: B[k][n], n = nt*16+n16, k = kk*32 + quad*8 + j
  bf16x8 bfr[4][4];
#pragma unroll
  for (int nt = 0; nt < 4; ++nt)
#pragma unroll
    for (int kk = 0; kk < 4; ++kk)
      bfr[nt][kk] = *(const bf16x8*)(sR + (nt * 16 + n16) * 136 + kk * 32 + quad * 8);

  // A fragments: row = wave*16 + n16, k = kk*32 + quad*8 + j, direct global
  const int arow = wave * 16 + n16;
  const float* xp = src + (row0 + arow) * DH;
  bf16x8 a[4];
#pragma unroll
  for (int kk = 0; kk < 4; ++kk) {
    const int k0 = kk * 32 + quad * 8;
    f32x4 x0 = *(const f32x4*)(xp + k0);
    f32x4 x1 = *(const f32x4*)(xp + k0 + 4);
    bf16x8 av;
#pragma unroll
    for (int j = 0; j < 4; ++j) { av[j] = (bf16_t)(x0[j] * scale); av[4 + j] = (bf16_t)(x1[j] * scale); }
    a[kk] = av;
  }

  bf16_t* sy = sYb + wave * (16 * 72);
#pragma unroll
  for (int nt = 0; nt < 4; ++nt) {
    f32x4 acc = {0.f, 0.f, 0.f, 0.f};
#pragma unroll
    for (int kk = 0; kk < 4; ++kk)
      acc = __builtin_amdgcn_mfma_f32_16x16x32_bf16(a[kk], bfr[nt][kk], acc, 0, 0, 0);
#pragma unroll
    for (int r = 0; r < 4; ++r)
      sy[(quad * 4 + r) * 72 + nt * 16 + n16] = (bf16_t)acc[r];
  }
  // coalesced store: lane -> (row = lane>>2, colgroup = lane&3)
  const long xrow = row0 + wave * 16;
  const int row = lane >> 2, cg = lane & 3;
  bf16x8 w0 = *(const bf16x8*)(&sy[row * 72 + cg * 16]);
  bf16x8 w1 = *(const bf16x8*)(&sy[row * 72 + cg * 16 + 8]);
  *(bf16x8*)(Y + (xrow + row) * PDIM + cg * 16)     = w0;
  *(bf16x8*)(Y + (xrow + row) * PDIM + cg * 16 + 8) = w1;
}

// ---------------------------------------------------------------------------
// flash v4 — BYTE-IDENTICAL to the round-0 source (proven 71.2 us).
// r1-r3 showed ANY source perturbation (issue-early DMA, KVB=128, even
// setprio insertion) tips regalloc into spilling the f32x16 accumulators
// (FETCH/WRITE inflate 5-10x). Do not touch this kernel.
// ---------------------------------------------------------------------------
__global__ __launch_bounds__(128, 2) void flash_kernel(
    const bf16_t* __restrict__ Qp, const bf16_t* __restrict__ Kp,
    const bf16_t* __restrict__ Vt, bf16_t* __restrict__ Opart,
    float* __restrict__ Lpart, float* __restrict__ Out,
    int splits, int iters)
{
  __shared__ char smem[24576];
  bf16_t* sK = (bf16_t*)smem;            // 64 rows x 64, swizzled chunks (8 KB)
  bf16_t* sV = (bf16_t*)(smem + 8192);   // 128 rows x 64, swizzled (16 KB)

  const int tid  = threadIdx.x;
  const int wave = tid >> 6, lane = tid & 63;
  const int l31  = lane & 31, h = lane >> 5;

  const int head = blockIdx.x & 15;      // XCD round-robin -> 2 heads/XCD
  const int qt   = (blockIdx.x >> 4) & 15;
  const int sp   = blockIdx.x >> 8;

  const int qbase = qt * 128 + wave * 64;
  const int kv0   = sp * (64 * iters);

  // persistent Q B-frags: B[k=p][n=q], q = qsub*32+l31, p = k*16 + 8h + j
  bf16x8 qf[2][4];
#pragma unroll
  for (int qsub = 0; qsub < 2; ++qsub)
#pragma unroll
    for (int k = 0; k < 4; ++k)
      qf[qsub][k] = *(const bf16x8*)(Qp + ((long)head * NQ + qbase + qsub * 32 + l31) * PDIM
                                     + k * 16 + h * 8);

  f32x16 o[2][4] = {};          // O^T accum: [qsub][dsub], C layout
  float rsum[2] = {0.f, 0.f};   // per-lane partial row sums

  const bf16_t* kpH = Kp + (long)head * NKV * PDIM;
  const bf16_t* vtH = Vt + (long)head * DH * NKV;

  const int sw = ((lane & 7) ^ ((lane >> 3) & 7)) * 8;  // src-col swizzle (elems)
  const int r8 = lane >> 3;                             // row within 8-row group

  for (int t = 0; t < iters; ++t) {
    const int kvb = kv0 + t * 64;
    __syncthreads();
    if (wave == 0) {
#pragma unroll
      for (int i = 0; i < 8; ++i)
        dma16(kpH + (long)(kvb + i * 8 + r8) * PDIM + sw, smem + i * 1024);
#pragma unroll
      for (int i = 0; i < 4; ++i)
        dma16(vtH + (long)(i * 8 + r8) * NKV + kvb + sw, smem + 8192 + i * 1024);
    } else {
#pragma unroll
      for (int i = 4; i < 16; ++i)
        dma16(vtH + (long)(i * 8 + r8) * NKV + kvb + sw, smem + 8192 + i * 1024);
    }
    __syncthreads();

#pragma unroll
    for (int s = 0; s < 2; ++s) {
      int bfr[2][2][4];   // P^T B-frags: [qsub][cl][4 x b32]
#pragma unroll
      for (int qsub = 0; qsub < 2; ++qsub) {
        // QK: S^T tile [32 kv][32 q], kv row = s*32 + l31
        f32x16 sc = {};
        const int r = s * 32 + l31;
#pragma unroll
        for (int k = 0; k < 4; ++k) {
          const int c = 2 * k + h;
          const bf16x8 a = *(const bf16x8*)(sK + r * 64 + ((c ^ (r & 7)) * 8));
          sc = __builtin_amdgcn_mfma_f32_32x32x16_bf16(a, qf[qsub][k], sc, 0, 0, 0);
        }
        // exp2 (log2-domain, fixed max 0) + pack + per-lane rsum
        int pk[4][2];
#pragma unroll
        for (int rg = 0; rg < 4; ++rg) {
          const float p0 = __builtin_amdgcn_exp2f(sc[rg * 4 + 0]);
          const float p1 = __builtin_amdgcn_exp2f(sc[rg * 4 + 1]);
          const float p2 = __builtin_amdgcn_exp2f(sc[rg * 4 + 2]);
          const float p3 = __builtin_amdgcn_exp2f(sc[rg * 4 + 3]);
          rsum[qsub] += (p0 + p1) + (p2 + p3);
          union { bf16x2 v; int i; } u0, u1;
          u0.v = bf16x2{(bf16_t)p0, (bf16_t)p1};
          u1.v = bf16x2{(bf16_t)p2, (bf16_t)p3};
          pk[rg][0] = u0.i; pk[rg][1] = u1.i;
        }
        // C-layout -> B-layout: j0-3 = half0's pk[2cl+h], j4-7 = half1's
#pragma unroll
        for (int cl = 0; cl < 2; ++cl) {
          const int e00 = __shfl_xor(pk[2 * cl][0], 32);
          const int e01 = __shfl_xor(pk[2 * cl][1], 32);
          const int e10 = __shfl_xor(pk[2 * cl + 1][0], 32);
          const int e11 = __shfl_xor(pk[2 * cl + 1][1], 32);
          bfr[qsub][cl][0] = h ? e10 : pk[2 * cl][0];
          bfr[qsub][cl][1] = h ? e11 : pk[2 * cl][1];
          bfr[qsub][cl][2] = h ? pk[2 * cl + 1][0] : e00;
          bfr[qsub][cl][3] = h ? pk[2 * cl + 1][1] : e01;
        }
      }
      // PV for this s: kv steps c = 2s + cl
#pragma unroll
      for (int dsub = 0; dsub < 4; ++dsub) {
        const int r = dsub * 32 + l31;
#pragma unroll
        for (int cl = 0; cl < 2; ++cl) {
          const int c = 2 * (2 * s + cl) + h;
          const bf16x8 va = *(const bf16x8*)(sV + r * 64 + ((c ^ (r & 7)) * 8));
#pragma unroll
          for (int qsub = 0; qsub < 2; ++qsub) {
            union { i32x4 i; bf16x8 v; } pb;
            pb.i = i32x4{bfr[qsub][cl][0], bfr[qsub][cl][1],
                         bfr[qsub][cl][2], bfr[qsub][cl][3]};
            o[qsub][dsub] = __builtin_amdgcn_mfma_f32_32x32x16_bf16(va, pb.v, o[qsub][dsub], 0, 0, 0);
          }
        }
      }
    }
  }

  // epilogue: transpose O^T -> row-major via wave-private LDS, store coalesced
  __syncthreads();
  bf16_t* myT = (bf16_t*)(smem + wave * 8704);   // 32 rows x 272 B (136 elems)
#pragma unroll
  for (int qsub = 0; qsub < 2; ++qsub) {
    const float lsum = rsum[qsub] + __shfl_xor(rsum[qsub], 32);
    const float scale = (splits > 1) ? 1.0f : (1.0f / lsum);
#pragma unroll
    for (int dsub = 0; dsub < 4; ++dsub)
#pragma unroll
      for (int rg = 0; rg < 4; ++rg) {
        bf16x4 w = { (bf16_t)(o[qsub][dsub][rg * 4 + 0] * scale),
                     (bf16_t)(o[qsub][dsub][rg * 4 + 1] * scale),
                     (bf16_t)(o[qsub][dsub][rg * 4 + 2] * scale),
                     (bf16_t)(o[qsub][dsub][rg * 4 + 3] * scale) };
        *(bf16x4*)(myT + l31 * 136 + dsub * 32 + rg * 8 + h * 4) = w;
      }
    const int qglob = qbase + qsub * 32;
#pragma unroll
    for (int j = 0; j < 8; ++j) {
      const int ql = j * 4 + (lane >> 4);
      bf16x8 v = *(const bf16x8*)(myT + ql * 136 + (lane & 15) * 8);
      if (splits > 1) {
        *(bf16x8*)(Opart + (((long)sp * HEADS + head) * NQ + qglob + ql) * DH + (lane & 15) * 8) = v;
      } else {
        float* op = Out + ((long)head * NQ + qglob + ql) * DH + (lane & 15) * 8;
        f32x4 a = {(float)v[0], (float)v[1], (float)v[2], (float)v[3]};
        f32x4 b = {(float)v[4], (float)v[5], (float)v[6], (float)v[7]};
        *(f32x4*)op = a; *(f32x4*)(op + 4) = b;
      }
    }
    if (splits > 1 && h == 0)
      Lpart[((long)sp * HEADS + head) * NQ + qglob + l31] = lsum;
  }
}

// ---------------------------------------------------------------------------
// combine: Out[hq][d] = (sum_s Opart[s][hq][d]) / (sum_s Lpart[s][hq])
// (round-0 form, fixed 4 splits)
// ---------------------------------------------------------------------------
__global__ __launch_bounds__(256) void combine_kernel(
    const bf16_t* __restrict__ Opart, const float* __restrict__ Lpart,
    float* __restrict__ Out)
{
  const long idx = (long)blockIdx.x * 256 + threadIdx.x;
  const int  d8  = (int)(idx & 15);
  const long hq  = idx >> 4;
  float l = 0.f;
  float acc[8];
#pragma unroll
  for (int j = 0; j < 8; ++j) acc[j] = 0.f;
#pragma unroll
  for (int s = 0; s < 4; ++s) {
    l += Lpart[s * (long)(HEADS * NQ) + hq];
    bf16x8 v = *(const bf16x8*)(Opart + (s * (long)(HEADS * NQ) + hq) * DH + d8 * 8);
#pragma unroll
    for (int j = 0; j < 8; ++j) acc[j] += (float)v[j];
  }
  const float inv = 1.f / l;
  f32x4 o0 = { acc[0] * inv, acc[1] * inv, acc[2] * inv, acc[3] * inv };
  f32x4 o1 = { acc[4] * inv, acc[5] * inv, acc[6] * inv, acc[7] * inv };
  float* op = Out + hq * DH + d8 * 8;
  *(f32x4*)(op)     = o0;
  *(f32x4*)(op + 4) = o1;
}

// ---------------------------------------------------------------------------
extern "C" void kernel_launch(void* const* d_in, const int* in_sizes, int n_in,
                              void* d_out, int out_size, void* d_ws, size_t ws_size,
                              hipStream_t stream)
{
  const float* Q = (const float*)d_in[0];
  const float* K = (const float*)d_in[1];
  const float* V = (const float*)d_in[2];
  const float* R = (const float*)d_in[3];
  float* Out = (float*)d_out;

  char* ws = (char*)d_ws;
  bf16_t* Qp = (bf16_t*)(ws);                          //  4 MiB: [16][2048][64]
  bf16_t* Kp = (bf16_t*)(ws + (size_t)(4  << 20));     //  8 MiB: [16][4096][64]
  bf16_t* Vt = (bf16_t*)(ws + (size_t)(12 << 20));     // 16 MiB: [16][128][4096]
  bf16_t* Opart = (bf16_t*)(ws + (size_t)(28 << 20));  // 32 MiB: [4][16][2048][128]
  float*  Lpart = (float*)(ws + (size_t)(60 << 20));   //  0.5 MiB: [4][16][2048]

  const size_t need4 = (size_t)(60 << 20) + 4ull * HEADS * NQ * sizeof(float);
  const int splits = (ws_size >= need4) ? 4 : 1;
  const int iters  = NKV / (64 * splits);

  prep_kernel<<<2560, 256, 0, stream>>>(Q, K, V, R, Qp, Kp, Vt);
  flash_kernel<<<splits * 256, 128, 0, stream>>>(Qp, Kp, Vt, Opart, Lpart, Out,
                                                 splits, iters);
  if (splits == 4)
    combine_kernel<<<2048, 256, 0, stream>>>(Opart, Lpart, Out);
}

// Round 7
// 189.738 us; speedup vs baseline: 1.8542x; 1.0229x over previous
//
#include <hip/hip_runtime.h>

#define HEADS 16
#define NQ    2048
#define NKV   4096
#define DH    128
#define PDIM  64

typedef __bf16 bf16_t;
typedef bf16_t bf16x8 __attribute__((ext_vector_type(8)));
typedef bf16_t bf16x4 __attribute__((ext_vector_type(4)));
typedef bf16_t bf16x2 __attribute__((ext_vector_type(2)));
typedef float  f32x4  __attribute__((ext_vector_type(4)));
typedef float  f32x16 __attribute__((ext_vector_type(16)));
typedef int    i32x4  __attribute__((ext_vector_type(4)));

typedef __attribute__((address_space(3))) unsigned int       lds_u32;
typedef __attribute__((address_space(1))) const unsigned int glb_u32;

__device__ __forceinline__ void dma16(const void* g, void* l) {
  __builtin_amdgcn_global_load_lds((glb_u32*)g, (lds_u32*)l, 16, 0, 0);
}

// ---------------------------------------------------------------------------
// prep (r6-proven: merged 3-launch pipeline, 194.1 us total == r0 baseline):
//   blocks [0,512):      Q -> Qp (scaled by (1/8)*log2e)   [proj path]
//   blocks [512,1536):   K -> Kp                            [proj path]
//   blocks [1536,2560):  V -> Vt (bf16 transpose)           [vtrans path]
// ---------------------------------------------------------------------------
__global__ __launch_bounds__(256) void prep_kernel(
    const float* __restrict__ Q, const float* __restrict__ K,
    const float* __restrict__ V, const float* __restrict__ R,
    bf16_t* __restrict__ Qp, bf16_t* __restrict__ Kp, bf16_t* __restrict__ Vt)
{
  __shared__ char lds[32768];
  const int tid = threadIdx.x;
  const int bid = blockIdx.x;

  if (bid >= 1536) {
    // ---- V transpose path ----
    float* sF = (float*)lds;                   // 64 x 128 f32, granule-swizzled
    const int vb = bid - 1536;
    const float* tp = V + (long)vb * 64 * DH;
#pragma unroll
    for (int rep = 0; rep < 8; ++rep) {
      const int slot = tid + rep * 256;        // 2048 granules: 64 rows x 32
      const int j = slot >> 5, g = slot & 31;
      f32x4 v = *(const f32x4*)(tp + j * DH + g * 4);
      *(f32x4*)(&sF[j * 128 + ((g ^ ((j >> 3) & 7)) << 2)]) = v;
    }
    __syncthreads();

    const int h = vb >> 6, jt = vb & 63;
    bf16_t* op = Vt + (long)h * DH * NKV + jt * 64;
#pragma unroll
    for (int rep = 0; rep < 4; ++rep) {
      const int slot = tid + rep * 256;        // 1024 slots: 128 d x 8 j-groups
      const int d = slot >> 3, j8 = (slot & 7) * 8;
      const int key = slot & 7;                // == (j>>3)&7 for j in [j8,j8+8)
      const int gsw = (((d >> 2) ^ key) << 2) + (d & 3);
      bf16x8 w;
#pragma unroll
      for (int jj = 0; jj < 8; ++jj) w[jj] = (bf16_t)sF[(j8 + jj) * 128 + gsw];
      *(bf16x8*)(op + (long)d * NKV + j8) = w;
    }
    return;
  }

  // ---- projection path (Q or K) ----
  bf16_t* sR = (bf16_t*)lds;                   // [64][136] bf16 (17.4 KB)
  bf16_t* sYb = (bf16_t*)(lds + 64 * 136 * 2); // 4 x [16*72] bf16 (9.2 KB)

  const int isQ = (bid < 512);
  const float* src = isQ ? Q : K;
  const long row0  = isQ ? (long)bid * 64 : (long)(bid - 512) * 64;
  const float scale = isQ ? 0.18033688011112042f : 1.0f;   // (1/8)*log2(e)
  bf16_t* Y = isQ ? Qp : Kp;

  // R -> LDS transpose: sR[n][k] = R[k][n]; reads R linearly (coalesced).
#pragma unroll
  for (int rep = 0; rep < 32; ++rep) {
    const int idx = tid + rep * 256;           // 8192 elems, k = idx>>6, n low
    sR[(idx & 63) * 136 + (idx >> 6)] = (bf16_t)R[idx];
  }
  __syncthreads();

  const int wave = tid >> 6, lane = tid & 63;
  const int n16  = lane & 15, quad = lane >> 4;

  // B fragments: B[k][n], n = nt*16+n16, k = kk*32 + quad*8 + j
  bf16x8 bfr[4][4];
#pragma unroll
  for (int nt = 0; nt < 4; ++nt)
#pragma unroll
    for (int kk = 0; kk < 4; ++kk)
      bfr[nt][kk] = *(const bf16x8*)(sR + (nt * 16 + n16) * 136 + kk * 32 + quad * 8);

  // A fragments: row = wave*16 + n16, k = kk*32 + quad*8 + j, direct global
  const int arow = wave * 16 + n16;
  const float* xp = src + (row0 + arow) * DH;
  bf16x8 a[4];
#pragma unroll
  for (int kk = 0; kk < 4; ++kk) {
    const int k0 = kk * 32 + quad * 8;
    f32x4 x0 = *(const f32x4*)(xp + k0);
    f32x4 x1 = *(const f32x4*)(xp + k0 + 4);
    bf16x8 av;
#pragma unroll
    for (int j = 0; j < 4; ++j) { av[j] = (bf16_t)(x0[j] * scale); av[4 + j] = (bf16_t)(x1[j] * scale); }
    a[kk] = av;
  }

  bf16_t* sy = sYb + wave * (16 * 72);
#pragma unroll
  for (int nt = 0; nt < 4; ++nt) {
    f32x4 acc = {0.f, 0.f, 0.f, 0.f};
#pragma unroll
    for (int kk = 0; kk < 4; ++kk)
      acc = __builtin_amdgcn_mfma_f32_16x16x32_bf16(a[kk], bfr[nt][kk], acc, 0, 0, 0);
#pragma unroll
    for (int r = 0; r < 4; ++r)
      sy[(quad * 4 + r) * 72 + nt * 16 + n16] = (bf16_t)acc[r];
  }
  // coalesced store: lane -> (row = lane>>2, colgroup = lane&3)
  const long xrow = row0 + wave * 16;
  const int row = lane >> 2, cg = lane & 3;
  bf16x8 w0 = *(const bf16x8*)(&sy[row * 72 + cg * 16]);
  bf16x8 w1 = *(const bf16x8*)(&sy[row * 72 + cg * 16 + 8]);
  *(bf16x8*)(Y + (xrow + row) * PDIM + cg * 16)     = w0;
  *(bf16x8*)(Y + (xrow + row) * PDIM + cg * 16 + 8) = w1;
}

// ---------------------------------------------------------------------------
// flash v9 — deliberate register-shrunk rewrite (NOT a perturbation of v4):
//   * 4 waves x 32 q-rows each (was 2 waves x 64 q). Same 128-q block tile,
//     same grid count (splits*256 blocks), same LDS staging layout, same
//     per-qsub math — the qsub loop simply disappears.
//   * accumulator halves: o[4] f32x16 = 64 regs/wave (was 128). Peak live
//     ~155 regs -> __launch_bounds__(256, 3) requests 3 waves/SIMD
//     (12 waves/CU vs v4's 8) with real headroom, not a forced cap.
//   * DMA issue: 6 dma16/wave/iter (was 12).
//   * epilogue LDS: 4 x 8704 B = 34.8 KB (still 4 blocks/CU by LDS).
// Spill check: FETCH ~19 MB / WRITE ~42.5 MB must stay; else revert to v4.
// ---------------------------------------------------------------------------
__global__ __launch_bounds__(256, 3) void flash_kernel(
    const bf16_t* __restrict__ Qp, const bf16_t* __restrict__ Kp,
    const bf16_t* __restrict__ Vt, bf16_t* __restrict__ Opart,
    float* __restrict__ Lpart, float* __restrict__ Out,
    int splits, int iters)
{
  __shared__ char smem[34816];           // staging 24.6 KB; epilogue 34.8 KB
  bf16_t* sK = (bf16_t*)smem;            // 64 rows x 64, swizzled chunks (8 KB)
  bf16_t* sV = (bf16_t*)(smem + 8192);   // 128 rows x 64, swizzled (16 KB)

  const int tid  = threadIdx.x;
  const int wave = tid >> 6, lane = tid & 63;
  const int l31  = lane & 31, h = lane >> 5;

  const int head = blockIdx.x & 15;      // XCD round-robin -> 2 heads/XCD
  const int qt   = (blockIdx.x >> 4) & 15;
  const int sp   = blockIdx.x >> 8;

  const int qbase = qt * 128 + wave * 32;   // each wave owns 32 q rows
  const int kv0   = sp * (64 * iters);

  // persistent Q B-frags: B[k=p][n=q], q = l31, p = k*16 + 8h + j
  bf16x8 qf[4];
#pragma unroll
  for (int k = 0; k < 4; ++k)
    qf[k] = *(const bf16x8*)(Qp + ((long)head * NQ + qbase + l31) * PDIM
                             + k * 16 + h * 8);

  f32x16 o[4] = {};             // O^T accum: [dsub], C layout (64 regs)
  float rsum = 0.f;             // per-lane partial row sum

  const bf16_t* kpH = Kp + (long)head * NKV * PDIM;
  const bf16_t* vtH = Vt + (long)head * DH * NKV;

  const int sw = ((lane & 7) ^ ((lane >> 3) & 7)) * 8;  // src-col swizzle (elems)
  const int r8 = lane >> 3;                             // row within 8-row group

  for (int t = 0; t < iters; ++t) {
    const int kvb = kv0 + t * 64;
    __syncthreads();
    // 24 dma16 chunks: 0..7 = K (8 KB), 8..23 = V (16 KB); 6 per wave.
    if (wave == 0) {
#pragma unroll
      for (int i = 0; i < 6; ++i)
        dma16(kpH + (long)(kvb + i * 8 + r8) * PDIM + sw, smem + i * 1024);
    } else if (wave == 1) {
#pragma unroll
      for (int i = 6; i < 8; ++i)
        dma16(kpH + (long)(kvb + i * 8 + r8) * PDIM + sw, smem + i * 1024);
#pragma unroll
      for (int i = 0; i < 4; ++i)
        dma16(vtH + (long)(i * 8 + r8) * NKV + kvb + sw, smem + 8192 + i * 1024);
    } else if (wave == 2) {
#pragma unroll
      for (int i = 4; i < 10; ++i)
        dma16(vtH + (long)(i * 8 + r8) * NKV + kvb + sw, smem + 8192 + i * 1024);
    } else {
#pragma unroll
      for (int i = 10; i < 16; ++i)
        dma16(vtH + (long)(i * 8 + r8) * NKV + kvb + sw, smem + 8192 + i * 1024);
    }
    __syncthreads();

#pragma unroll
    for (int s = 0; s < 2; ++s) {
      // QK: S^T tile [32 kv][32 q], kv row = s*32 + l31
      f32x16 sc = {};
      const int r = s * 32 + l31;
#pragma unroll
      for (int k = 0; k < 4; ++k) {
        const int c = 2 * k + h;
        const bf16x8 a = *(const bf16x8*)(sK + r * 64 + ((c ^ (r & 7)) * 8));
        sc = __builtin_amdgcn_mfma_f32_32x32x16_bf16(a, qf[k], sc, 0, 0, 0);
      }
      // exp2 (log2-domain, fixed max 0) + pack + per-lane rsum
      int pk[4][2];
#pragma unroll
      for (int rg = 0; rg < 4; ++rg) {
        const float p0 = __builtin_amdgcn_exp2f(sc[rg * 4 + 0]);
        const float p1 = __builtin_amdgcn_exp2f(sc[rg * 4 + 1]);
        const float p2 = __builtin_amdgcn_exp2f(sc[rg * 4 + 2]);
        const float p3 = __builtin_amdgcn_exp2f(sc[rg * 4 + 3]);
        rsum += (p0 + p1) + (p2 + p3);
        union { bf16x2 v; int i; } u0, u1;
        u0.v = bf16x2{(bf16_t)p0, (bf16_t)p1};
        u1.v = bf16x2{(bf16_t)p2, (bf16_t)p3};
        pk[rg][0] = u0.i; pk[rg][1] = u1.i;
      }
      // C-layout -> B-layout: j0-3 = half0's pk[2cl+h], j4-7 = half1's
      int bfr[2][4];
#pragma unroll
      for (int cl = 0; cl < 2; ++cl) {
        const int e00 = __shfl_xor(pk[2 * cl][0], 32);
        const int e01 = __shfl_xor(pk[2 * cl][1], 32);
        const int e10 = __shfl_xor(pk[2 * cl + 1][0], 32);
        const int e11 = __shfl_xor(pk[2 * cl + 1][1], 32);
        bfr[cl][0] = h ? e10 : pk[2 * cl][0];
        bfr[cl][1] = h ? e11 : pk[2 * cl][1];
        bfr[cl][2] = h ? pk[2 * cl + 1][0] : e00;
        bfr[cl][3] = h ? pk[2 * cl + 1][1] : e01;
      }
      // PV for this s: kv steps c = 2s + cl
#pragma unroll
      for (int dsub = 0; dsub < 4; ++dsub) {
        const int rr = dsub * 32 + l31;
#pragma unroll
        for (int cl = 0; cl < 2; ++cl) {
          const int c = 2 * (2 * s + cl) + h;
          const bf16x8 va = *(const bf16x8*)(sV + rr * 64 + ((c ^ (rr & 7)) * 8));
          union { i32x4 i; bf16x8 v; } pb;
          pb.i = i32x4{bfr[cl][0], bfr[cl][1], bfr[cl][2], bfr[cl][3]};
          o[dsub] = __builtin_amdgcn_mfma_f32_32x32x16_bf16(va, pb.v, o[dsub], 0, 0, 0);
        }
      }
    }
  }

  // epilogue: transpose O^T -> row-major via wave-private LDS, store coalesced
  __syncthreads();
  bf16_t* myT = (bf16_t*)(smem + wave * 8704);   // 32 rows x 272 B (136 elems)
  const float lsum = rsum + __shfl_xor(rsum, 32);
  const float scale = (splits > 1) ? 1.0f : (1.0f / lsum);
#pragma unroll
  for (int dsub = 0; dsub < 4; ++dsub)
#pragma unroll
    for (int rg = 0; rg < 4; ++rg) {
      bf16x4 w = { (bf16_t)(o[dsub][rg * 4 + 0] * scale),
                   (bf16_t)(o[dsub][rg * 4 + 1] * scale),
                   (bf16_t)(o[dsub][rg * 4 + 2] * scale),
                   (bf16_t)(o[dsub][rg * 4 + 3] * scale) };
      *(bf16x4*)(myT + l31 * 136 + dsub * 32 + rg * 8 + h * 4) = w;
    }
#pragma unroll
  for (int j = 0; j < 8; ++j) {
    const int ql = j * 4 + (lane >> 4);
    bf16x8 v = *(const bf16x8*)(myT + ql * 136 + (lane & 15) * 8);
    if (splits > 1) {
      *(bf16x8*)(Opart + (((long)sp * HEADS + head) * NQ + qbase + ql) * DH + (lane & 15) * 8) = v;
    } else {
      float* op = Out + ((long)head * NQ + qbase + ql) * DH + (lane & 15) * 8;
      f32x4 a = {(float)v[0], (float)v[1], (float)v[2], (float)v[3]};
      f32x4 b = {(float)v[4], (float)v[5], (float)v[6], (float)v[7]};
      *(f32x4*)op = a; *(f32x4*)(op + 4) = b;
    }
  }
  if (splits > 1 && h == 0)
    Lpart[((long)sp * HEADS + head) * NQ + qbase + l31] = lsum;
}

// ---------------------------------------------------------------------------
// combine: Out[hq][d] = (sum_s Opart[s][hq][d]) / (sum_s Lpart[s][hq])
// (round-0 form, fixed 4 splits)
// ---------------------------------------------------------------------------
__global__ __launch_bounds__(256) void combine_kernel(
    const bf16_t* __restrict__ Opart, const float* __restrict__ Lpart,
    float* __restrict__ Out)
{
  const long idx = (long)blockIdx.x * 256 + threadIdx.x;
  const int  d8  = (int)(idx & 15);
  const long hq  = idx >> 4;
  float l = 0.f;
  float acc[8];
#pragma unroll
  for (int j = 0; j < 8; ++j) acc[j] = 0.f;
#pragma unroll
  for (int s = 0; s < 4; ++s) {
    l += Lpart[s * (long)(HEADS * NQ) + hq];
    bf16x8 v = *(const bf16x8*)(Opart + (s * (long)(HEADS * NQ) + hq) * DH + d8 * 8);
#pragma unroll
    for (int j = 0; j < 8; ++j) acc[j] += (float)v[j];
  }
  const float inv = 1.f / l;
  f32x4 o0 = { acc[0] * inv, acc[1] * inv, acc[2] * inv, acc[3] * inv };
  f32x4 o1 = { acc[4] * inv, acc[5] * inv, acc[6] * inv, acc[7] * inv };
  float* op = Out + hq * DH + d8 * 8;
  *(f32x4*)(op)     = o0;
  *(f32x4*)(op + 4) = o1;
}

// ---------------------------------------------------------------------------
extern "C" void kernel_launch(void* const* d_in, const int* in_sizes, int n_in,
                              void* d_out, int out_size, void* d_ws, size_t ws_size,
                              hipStream_t stream)
{
  const float* Q = (const float*)d_in[0];
  const float* K = (const float*)d_in[1];
  const float* V = (const float*)d_in[2];
  const float* R = (const float*)d_in[3];
  float* Out = (float*)d_out;

  char* ws = (char*)d_ws;
  bf16_t* Qp = (bf16_t*)(ws);                          //  4 MiB: [16][2048][64]
  bf16_t* Kp = (bf16_t*)(ws + (size_t)(4  << 20));     //  8 MiB: [16][4096][64]
  bf16_t* Vt = (bf16_t*)(ws + (size_t)(12 << 20));     // 16 MiB: [16][128][4096]
  bf16_t* Opart = (bf16_t*)(ws + (size_t)(28 << 20));  // 32 MiB: [4][16][2048][128]
  float*  Lpart = (float*)(ws + (size_t)(60 << 20));   //  0.5 MiB: [4][16][2048]

  const size_t need4 = (size_t)(60 << 20) + 4ull * HEADS * NQ * sizeof(float);
  const int splits = (ws_size >= need4) ? 4 : 1;
  const int iters  = NKV / (64 * splits);

  prep_kernel<<<2560, 256, 0, stream>>>(Q, K, V, R, Qp, Kp, Vt);
  flash_kernel<<<splits * 256, 256, 0, stream>>>(Qp, Kp, Vt, Opart, Lpart, Out,
                                                 splits, iters);
  if (splits == 4)
    combine_kernel<<<2048, 256, 0, stream>>>(Opart, Lpart, Out);
}

// Round 8
// 186.223 us; speedup vs baseline: 1.8892x; 1.0189x over previous
//
#include <hip/hip_runtime.h>

#define HEADS 16
#define NQ    2048
#define NKV   4096
#define DH    128
#define PDIM  64

typedef __bf16 bf16_t;
typedef bf16_t bf16x8 __attribute__((ext_vector_type(8)));
typedef bf16_t bf16x4 __attribute__((ext_vector_type(4)));
typedef bf16_t bf16x2 __attribute__((ext_vector_type(2)));
typedef float  f32x4  __attribute__((ext_vector_type(4)));
typedef float  f32x16 __attribute__((ext_vector_type(16)));
typedef int    i32x4  __attribute__((ext_vector_type(4)));

typedef __attribute__((address_space(3))) unsigned int       lds_u32;
typedef __attribute__((address_space(1))) const unsigned int glb_u32;

__device__ __forceinline__ void dma16(const void* g, void* l) {
  __builtin_amdgcn_global_load_lds((glb_u32*)g, (lds_u32*)l, 16, 0, 0);
}

// ---------------------------------------------------------------------------
// prep (r6-proven: merged 3-launch pipeline):
//   blocks [0,512):      Q -> Qp (scaled by (1/8)*log2e)   [proj path]
//   blocks [512,1536):   K -> Kp                            [proj path]
//   blocks [1536,2560):  V -> Vt (bf16 transpose)           [vtrans path]
// ---------------------------------------------------------------------------
__global__ __launch_bounds__(256) void prep_kernel(
    const float* __restrict__ Q, const float* __restrict__ K,
    const float* __restrict__ V, const float* __restrict__ R,
    bf16_t* __restrict__ Qp, bf16_t* __restrict__ Kp, bf16_t* __restrict__ Vt)
{
  __shared__ char lds[32768];
  const int tid = threadIdx.x;
  const int bid = blockIdx.x;

  if (bid >= 1536) {
    // ---- V transpose path ----
    float* sF = (float*)lds;                   // 64 x 128 f32, granule-swizzled
    const int vb = bid - 1536;
    const float* tp = V + (long)vb * 64 * DH;
#pragma unroll
    for (int rep = 0; rep < 8; ++rep) {
      const int slot = tid + rep * 256;        // 2048 granules: 64 rows x 32
      const int j = slot >> 5, g = slot & 31;
      f32x4 v = *(const f32x4*)(tp + j * DH + g * 4);
      *(f32x4*)(&sF[j * 128 + ((g ^ ((j >> 3) & 7)) << 2)]) = v;
    }
    __syncthreads();

    const int h = vb >> 6, jt = vb & 63;
    bf16_t* op = Vt + (long)h * DH * NKV + jt * 64;
#pragma unroll
    for (int rep = 0; rep < 4; ++rep) {
      const int slot = tid + rep * 256;        // 1024 slots: 128 d x 8 j-groups
      const int d = slot >> 3, j8 = (slot & 7) * 8;
      const int key = slot & 7;                // == (j>>3)&7 for j in [j8,j8+8)
      const int gsw = (((d >> 2) ^ key) << 2) + (d & 3);
      bf16x8 w;
#pragma unroll
      for (int jj = 0; jj < 8; ++jj) w[jj] = (bf16_t)sF[(j8 + jj) * 128 + gsw];
      *(bf16x8*)(op + (long)d * NKV + j8) = w;
    }
    return;
  }

  // ---- projection path (Q or K) ----
  bf16_t* sR = (bf16_t*)lds;                   // [64][136] bf16 (17.4 KB)
  bf16_t* sYb = (bf16_t*)(lds + 64 * 136 * 2); // 4 x [16*72] bf16 (9.2 KB)

  const int isQ = (bid < 512);
  const float* src = isQ ? Q : K;
  const long row0  = isQ ? (long)bid * 64 : (long)(bid - 512) * 64;
  const float scale = isQ ? 0.18033688011112042f : 1.0f;   // (1/8)*log2(e)
  bf16_t* Y = isQ ? Qp : Kp;

  // R -> LDS transpose: sR[n][k] = R[k][n]; reads R linearly (coalesced).
#pragma unroll
  for (int rep = 0; rep < 32; ++rep) {
    const int idx = tid + rep * 256;           // 8192 elems, k = idx>>6, n low
    sR[(idx & 63) * 136 + (idx >> 6)] = (bf16_t)R[idx];
  }
  __syncthreads();

  const int wave = tid >> 6, lane = tid & 63;
  const int n16  = lane & 15, quad = lane >> 4;

  // B fragments: B[k][n], n = nt*16+n16, k = kk*32 + quad*8 + j
  bf16x8 bfr[4][4];
#pragma unroll
  for (int nt = 0; nt < 4; ++nt)
#pragma unroll
    for (int kk = 0; kk < 4; ++kk)
      bfr[nt][kk] = *(const bf16x8*)(sR + (nt * 16 + n16) * 136 + kk * 32 + quad * 8);

  // A fragments: row = wave*16 + n16, k = kk*32 + quad*8 + j, direct global
  const int arow = wave * 16 + n16;
  const float* xp = src + (row0 + arow) * DH;
  bf16x8 a[4];
#pragma unroll
  for (int kk = 0; kk < 4; ++kk) {
    const int k0 = kk * 32 + quad * 8;
    f32x4 x0 = *(const f32x4*)(xp + k0);
    f32x4 x1 = *(const f32x4*)(xp + k0 + 4);
    bf16x8 av;
#pragma unroll
    for (int j = 0; j < 4; ++j) { av[j] = (bf16_t)(x0[j] * scale); av[4 + j] = (bf16_t)(x1[j] * scale); }
    a[kk] = av;
  }

  bf16_t* sy = sYb + wave * (16 * 72);
#pragma unroll
  for (int nt = 0; nt < 4; ++nt) {
    f32x4 acc = {0.f, 0.f, 0.f, 0.f};
#pragma unroll
    for (int kk = 0; kk < 4; ++kk)
      acc = __builtin_amdgcn_mfma_f32_16x16x32_bf16(a[kk], bfr[nt][kk], acc, 0, 0, 0);
#pragma unroll
    for (int r = 0; r < 4; ++r)
      sy[(quad * 4 + r) * 72 + nt * 16 + n16] = (bf16_t)acc[r];
  }
  // coalesced store: lane -> (row = lane>>2, colgroup = lane&3)
  const long xrow = row0 + wave * 16;
  const int row = lane >> 2, cg = lane & 3;
  bf16x8 w0 = *(const bf16x8*)(&sy[row * 72 + cg * 16]);
  bf16x8 w1 = *(const bf16x8*)(&sy[row * 72 + cg * 16 + 8]);
  *(bf16x8*)(Y + (xrow + row) * PDIM + cg * 16)     = w0;
  *(bf16x8*)(Y + (xrow + row) * PDIM + cg * 16 + 8) = w1;
}

// ---------------------------------------------------------------------------
// flash v10 = v4's read-amortized inner body (qsub=2: each sK/sV ds_read
// feeds TWO MFMAs — 0.5 reads/MFMA) x v9's 4-wave block structure.
// Rationale (r7 calibrated model): MFMA floor 20.7 us (m119: 32 cyc/instr/
// SIMD) matches MfmaUtil 31%; LDS read time ~42 us dominates. v9 doubled
// reads/MFMA vs v4 (no qsub), which canceled its occupancy gain. v10
// halves total ds_reads (1.57M -> 786K) at unchanged MFMA count.
//   * 4 waves x 64 q = 256-q tile, splits*128 blocks of 256 threads.
//   * registers: v4's proven budget (128 acc + ~128 arch, 2 waves/SIMD).
//   * staging: r7-proven 6-dma16/wave split, KVB=64, single-buffered.
//   * sK read hoisted out of the qsub loop (what the compiler did in v4).
// Spill tripwire: FETCH ~14 MB / WRITE ~33 MB must hold; else revert v9.
// ---------------------------------------------------------------------------
__global__ __launch_bounds__(256, 2) void flash_kernel(
    const bf16_t* __restrict__ Qp, const bf16_t* __restrict__ Kp,
    const bf16_t* __restrict__ Vt, bf16_t* __restrict__ Opart,
    float* __restrict__ Lpart, float* __restrict__ Out,
    int splits, int iters)
{
  __shared__ char smem[34816];           // staging 24.6 KB; epilogue 34.8 KB
  bf16_t* sK = (bf16_t*)smem;            // 64 rows x 64, swizzled chunks (8 KB)
  bf16_t* sV = (bf16_t*)(smem + 8192);   // 128 rows x 64, swizzled (16 KB)

  const int tid  = threadIdx.x;
  const int wave = tid >> 6, lane = tid & 63;
  const int l31  = lane & 31, h = lane >> 5;

  const int head = blockIdx.x & 15;      // XCD round-robin -> 2 heads/XCD
  const int qt   = (blockIdx.x >> 4) & 7;
  const int sp   = blockIdx.x >> 7;

  const int qbase = qt * 256 + wave * 64;
  const int kv0   = sp * (64 * iters);

  // persistent Q B-frags: B[k=p][n=q], q = qsub*32+l31, p = k*16 + 8h + j
  bf16x8 qf[2][4];
#pragma unroll
  for (int qsub = 0; qsub < 2; ++qsub)
#pragma unroll
    for (int k = 0; k < 4; ++k)
      qf[qsub][k] = *(const bf16x8*)(Qp + ((long)head * NQ + qbase + qsub * 32 + l31) * PDIM
                                     + k * 16 + h * 8);

  f32x16 o[2][4] = {};          // O^T accum: [qsub][dsub], C layout
  float rsum[2] = {0.f, 0.f};   // per-lane partial row sums

  const bf16_t* kpH = Kp + (long)head * NKV * PDIM;
  const bf16_t* vtH = Vt + (long)head * DH * NKV;

  const int sw = ((lane & 7) ^ ((lane >> 3) & 7)) * 8;  // src-col swizzle (elems)
  const int r8 = lane >> 3;                             // row within 8-row group

  for (int t = 0; t < iters; ++t) {
    const int kvb = kv0 + t * 64;
    __syncthreads();
    // 24 dma16 chunks: 0..7 = K (8 KB), 8..23 = V (16 KB); 6 per wave.
    if (wave == 0) {
#pragma unroll
      for (int i = 0; i < 6; ++i)
        dma16(kpH + (long)(kvb + i * 8 + r8) * PDIM + sw, smem + i * 1024);
    } else if (wave == 1) {
#pragma unroll
      for (int i = 6; i < 8; ++i)
        dma16(kpH + (long)(kvb + i * 8 + r8) * PDIM + sw, smem + i * 1024);
#pragma unroll
      for (int i = 0; i < 4; ++i)
        dma16(vtH + (long)(i * 8 + r8) * NKV + kvb + sw, smem + 8192 + i * 1024);
    } else if (wave == 2) {
#pragma unroll
      for (int i = 4; i < 10; ++i)
        dma16(vtH + (long)(i * 8 + r8) * NKV + kvb + sw, smem + 8192 + i * 1024);
    } else {
#pragma unroll
      for (int i = 10; i < 16; ++i)
        dma16(vtH + (long)(i * 8 + r8) * NKV + kvb + sw, smem + 8192 + i * 1024);
    }
    __syncthreads();

#pragma unroll
    for (int s = 0; s < 2; ++s) {
      // hoisted K A-frags: shared by both qsub MFMAs (0.5 reads/MFMA)
      const int r = s * 32 + l31;
      bf16x8 ak[4];
#pragma unroll
      for (int k = 0; k < 4; ++k) {
        const int c = 2 * k + h;
        ak[k] = *(const bf16x8*)(sK + r * 64 + ((c ^ (r & 7)) * 8));
      }
      int bfr[2][2][4];   // P^T B-frags: [qsub][cl][4 x b32]
#pragma unroll
      for (int qsub = 0; qsub < 2; ++qsub) {
        // QK: S^T tile [32 kv][32 q], kv row = s*32 + l31
        f32x16 sc = {};
#pragma unroll
        for (int k = 0; k < 4; ++k)
          sc = __builtin_amdgcn_mfma_f32_32x32x16_bf16(ak[k], qf[qsub][k], sc, 0, 0, 0);
        // exp2 (log2-domain, fixed max 0) + pack + per-lane rsum
        int pk[4][2];
#pragma unroll
        for (int rg = 0; rg < 4; ++rg) {
          const float p0 = __builtin_amdgcn_exp2f(sc[rg * 4 + 0]);
          const float p1 = __builtin_amdgcn_exp2f(sc[rg * 4 + 1]);
          const float p2 = __builtin_amdgcn_exp2f(sc[rg * 4 + 2]);
          const float p3 = __builtin_amdgcn_exp2f(sc[rg * 4 + 3]);
          rsum[qsub] += (p0 + p1) + (p2 + p3);
          union { bf16x2 v; int i; } u0, u1;
          u0.v = bf16x2{(bf16_t)p0, (bf16_t)p1};
          u1.v = bf16x2{(bf16_t)p2, (bf16_t)p3};
          pk[rg][0] = u0.i; pk[rg][1] = u1.i;
        }
        // C-layout -> B-layout: j0-3 = half0's pk[2cl+h], j4-7 = half1's
#pragma unroll
        for (int cl = 0; cl < 2; ++cl) {
          const int e00 = __shfl_xor(pk[2 * cl][0], 32);
          const int e01 = __shfl_xor(pk[2 * cl][1], 32);
          const int e10 = __shfl_xor(pk[2 * cl + 1][0], 32);
          const int e11 = __shfl_xor(pk[2 * cl + 1][1], 32);
          bfr[qsub][cl][0] = h ? e10 : pk[2 * cl][0];
          bfr[qsub][cl][1] = h ? e11 : pk[2 * cl][1];
          bfr[qsub][cl][2] = h ? pk[2 * cl + 1][0] : e00;
          bfr[qsub][cl][3] = h ? pk[2 * cl + 1][1] : e01;
        }
      }
      // PV for this s: kv steps c = 2s + cl; va read shared by both qsub
#pragma unroll
      for (int dsub = 0; dsub < 4; ++dsub) {
        const int rr = dsub * 32 + l31;
#pragma unroll
        for (int cl = 0; cl < 2; ++cl) {
          const int c = 2 * (2 * s + cl) + h;
          const bf16x8 va = *(const bf16x8*)(sV + rr * 64 + ((c ^ (rr & 7)) * 8));
#pragma unroll
          for (int qsub = 0; qsub < 2; ++qsub) {
            union { i32x4 i; bf16x8 v; } pb;
            pb.i = i32x4{bfr[qsub][cl][0], bfr[qsub][cl][1],
                         bfr[qsub][cl][2], bfr[qsub][cl][3]};
            o[qsub][dsub] = __builtin_amdgcn_mfma_f32_32x32x16_bf16(va, pb.v, o[qsub][dsub], 0, 0, 0);
          }
        }
      }
    }
  }

  // epilogue: transpose O^T -> row-major via wave-private LDS, store coalesced
  __syncthreads();
  bf16_t* myT = (bf16_t*)(smem + wave * 8704);   // 32 rows x 272 B (136 elems)
#pragma unroll
  for (int qsub = 0; qsub < 2; ++qsub) {
    const float lsum = rsum[qsub] + __shfl_xor(rsum[qsub], 32);
    const float scale = (splits > 1) ? 1.0f : (1.0f / lsum);
#pragma unroll
    for (int dsub = 0; dsub < 4; ++dsub)
#pragma unroll
      for (int rg = 0; rg < 4; ++rg) {
        bf16x4 w = { (bf16_t)(o[qsub][dsub][rg * 4 + 0] * scale),
                     (bf16_t)(o[qsub][dsub][rg * 4 + 1] * scale),
                     (bf16_t)(o[qsub][dsub][rg * 4 + 2] * scale),
                     (bf16_t)(o[qsub][dsub][rg * 4 + 3] * scale) };
        *(bf16x4*)(myT + l31 * 136 + dsub * 32 + rg * 8 + h * 4) = w;
      }
    const int qglob = qbase + qsub * 32;
#pragma unroll
    for (int j = 0; j < 8; ++j) {
      const int ql = j * 4 + (lane >> 4);
      bf16x8 v = *(const bf16x8*)(myT + ql * 136 + (lane & 15) * 8);
      if (splits > 1) {
        *(bf16x8*)(Opart + (((long)sp * HEADS + head) * NQ + qglob + ql) * DH + (lane & 15) * 8) = v;
      } else {
        float* op = Out + ((long)head * NQ + qglob + ql) * DH + (lane & 15) * 8;
        f32x4 a = {(float)v[0], (float)v[1], (float)v[2], (float)v[3]};
        f32x4 b = {(float)v[4], (float)v[5], (float)v[6], (float)v[7]};
        *(f32x4*)op = a; *(f32x4*)(op + 4) = b;
      }
    }
    if (splits > 1 && h == 0)
      Lpart[((long)sp * HEADS + head) * NQ + qglob + l31] = lsum;
  }
}

// ---------------------------------------------------------------------------
// combine: Out[hq][d] = (sum_s Opart[s][hq][d]) / (sum_s Lpart[s][hq])
// (round-0 form, fixed 4 splits)
// ---------------------------------------------------------------------------
__global__ __launch_bounds__(256) void combine_kernel(
    const bf16_t* __restrict__ Opart, const float* __restrict__ Lpart,
    float* __restrict__ Out)
{
  const long idx = (long)blockIdx.x * 256 + threadIdx.x;
  const int  d8  = (int)(idx & 15);
  const long hq  = idx >> 4;
  float l = 0.f;
  float acc[8];
#pragma unroll
  for (int j = 0; j < 8; ++j) acc[j] = 0.f;
#pragma unroll
  for (int s = 0; s < 4; ++s) {
    l += Lpart[s * (long)(HEADS * NQ) + hq];
    bf16x8 v = *(const bf16x8*)(Opart + (s * (long)(HEADS * NQ) + hq) * DH + d8 * 8);
#pragma unroll
    for (int j = 0; j < 8; ++j) acc[j] += (float)v[j];
  }
  const float inv = 1.f / l;
  f32x4 o0 = { acc[0] * inv, acc[1] * inv, acc[2] * inv, acc[3] * inv };
  f32x4 o1 = { acc[4] * inv, acc[5] * inv, acc[6] * inv, acc[7] * inv };
  float* op = Out + hq * DH + d8 * 8;
  *(f32x4*)(op)     = o0;
  *(f32x4*)(op + 4) = o1;
}

// ---------------------------------------------------------------------------
extern "C" void kernel_launch(void* const* d_in, const int* in_sizes, int n_in,
                              void* d_out, int out_size, void* d_ws, size_t ws_size,
                              hipStream_t stream)
{
  const float* Q = (const float*)d_in[0];
  const float* K = (const float*)d_in[1];
  const float* V = (const float*)d_in[2];
  const float* R = (const float*)d_in[3];
  float* Out = (float*)d_out;

  char* ws = (char*)d_ws;
  bf16_t* Qp = (bf16_t*)(ws);                          //  4 MiB: [16][2048][64]
  bf16_t* Kp = (bf16_t*)(ws + (size_t)(4  << 20));     //  8 MiB: [16][4096][64]
  bf16_t* Vt = (bf16_t*)(ws + (size_t)(12 << 20));     // 16 MiB: [16][128][4096]
  bf16_t* Opart = (bf16_t*)(ws + (size_t)(28 << 20));  // 32 MiB: [4][16][2048][128]
  float*  Lpart = (float*)(ws + (size_t)(60 << 20));   //  0.5 MiB: [4][16][2048]

  const size_t need4 = (size_t)(60 << 20) + 4ull * HEADS * NQ * sizeof(float);
  const int splits = (ws_size >= need4) ? 4 : 1;
  const int iters  = NKV / (64 * splits);

  prep_kernel<<<2560, 256, 0, stream>>>(Q, K, V, R, Qp, Kp, Vt);
  flash_kernel<<<splits * 128, 256, 0, stream>>>(Qp, Kp, Vt, Opart, Lpart, Out,
                                                 splits, iters);
  if (splits == 4)
    combine_kernel<<<2048, 256, 0, stream>>>(Opart, Lpart, Out);
}